// Round 12
// baseline (3246.795 us; speedup 1.0000x reference)
//
#include <hip/hip_runtime.h>
#include <math.h>

#define NB 8
#define SD 768
#define NHEAD 12
#define LMAX 197
#define QBLK 32
#define KBLK 64

typedef __attribute__((ext_vector_type(8))) short bf16x8;
typedef __attribute__((ext_vector_type(4))) float f32x4;
typedef const __attribute__((address_space(1))) unsigned int gu32_t;
typedef __attribute__((address_space(3))) unsigned int lu32_t;

static __device__ __forceinline__ float geluf(float x){
    return 0.5f*x*(1.0f+erff(x*0.70710678118654752440f));
}

static __device__ __forceinline__ void split_bf16(float v, ushort& h, ushort& l){
    uint u = __float_as_uint(v);
    uint hb = (u + 0x7FFFu + ((u>>16)&1u)) >> 16;
    h = (ushort)hb;
    float rem = v - __uint_as_float(hb<<16);
    uint u2 = __float_as_uint(rem);
    l = (ushort)((u2 + 0x7FFFu + ((u2>>16)&1u)) >> 16);
}

// ---- weight convert+transpose (batched): W[z][K][Nc] fp32 -> Hi/Lo[z][Nc][K]
__global__ __launch_bounds__(256) void wconv(const float* __restrict__ W,
        ushort* __restrict__ Hi, ushort* __restrict__ Lo, int K, int Nc)
{
    __shared__ float tile[32][33];
    int z = blockIdx.z;
    const float* Wz = W + (size_t)z*K*Nc;
    ushort* Hz = Hi + (size_t)z*Nc*K;
    ushort* Lz = Lo + (size_t)z*Nc*K;
    int n0 = blockIdx.x*32, k0 = blockIdx.y*32;
    int tx = threadIdx.x&31, ty = threadIdx.x>>5;
    #pragma unroll
    for (int i=0;i<32;i+=8) tile[ty+i][tx] = Wz[(size_t)(k0+ty+i)*Nc + n0+tx];
    __syncthreads();
    #pragma unroll
    for (int i=0;i<32;i+=8){
        float v = tile[tx][ty+i];
        ushort h,l; split_bf16(v,h,l);
        size_t o = (size_t)(n0+ty+i)*K + k0+tx;
        Hz[o]=h; Lz[o]=l;
    }
}

// ---- split-bf16 MFMA GEMM: BK=32, double-buffered 32KB LDS via
// global_load_lds, counted vmcnt(4). 1D grid with bijective XCD swizzle.
// Bank-conflict fix (both-sides swizzle): LDS[row][p] holds global 16B chunk
// p ^ ((row>>1)&3). setprio(1) around MFMA cluster (T5); trailing barrier
// dropped on the last K-step (no stage follows it).
template<int EPI, int SPLITK>
__global__ __launch_bounds__(256) void gemm_mfma(const ushort* __restrict__ AHi,
        const ushort* __restrict__ ALo, const ushort* __restrict__ WHi,
        const ushort* __restrict__ WLo, const float* __restrict__ bias,
        const float* __restrict__ R, float* __restrict__ C,
        ushort* __restrict__ CHi, ushort* __restrict__ CLo,
        float* __restrict__ Part, int M, int Nc, int K, int ntok, int gx)
{
    __shared__ __align__(16) ushort sAhi[2][2048], sAlo[2][2048];
    __shared__ __align__(16) ushort sBhi[2][2048], sBlo[2][2048];
    const int t = threadIdx.x;
    const int nwg = gridDim.x;
    const int qc = nwg>>3, rc = nwg&7;
    const int xcd = blockIdx.x & 7, jj = blockIdx.x >> 3;
    const int wid = (xcd<rc ? xcd*(qc+1) : rc*(qc+1)+(xcd-rc)*qc) + jj;
    const int bx = wid % gx;
    const int t2 = wid / gx;
    const int gy = nwg/(gx*SPLITK);
    const int by = t2 % gy;
    const int bz = t2 / gy;

    const int w = t>>6, l = t&63, lr = l&15, lg = l>>4;
    const int wr = w>>1, wc = w&1;

    const int Ks = K/SPLITK;
    const int kbeg = bz*Ks;
    const int nt = Ks/32;

    const int srow = t>>2;
    const uint schunk = (uint)((((t&3) ^ ((t>>3)&3)))*16);
    int ar = by*64 + srow; if (ar >= M) ar = M-1;
    int ab_ = ar/ntok; int an_ = ar - ab_*ntok;
    size_t aoff = ((size_t)(ab_*LMAX+an_)*K + kbeg)*2 + schunk;
    size_t woff = ((size_t)(bx*64+srow)*K + kbeg)*2 + schunk;
    const char* pAh = (const char*)AHi + aoff;
    const char* pAl = (const char*)ALo + aoff;
    const char* pWh = (const char*)WHi + woff;
    const char* pWl = (const char*)WLo + woff;

    f32x4 acc[2][2];
    #pragma unroll
    for (int i=0;i<2;i++)
        #pragma unroll
        for (int j=0;j<2;j++) acc[i][j] = (f32x4){0.f,0.f,0.f,0.f};

    const uint wb = (uint)(w*512);

    auto stage = [&](int bf, int kt){
        size_t ko = (size_t)kt*64;
        __builtin_amdgcn_global_load_lds((gu32_t*)(pAh+ko), (lu32_t*)&sAhi[bf][wb], 16, 0, 0);
        __builtin_amdgcn_global_load_lds((gu32_t*)(pAl+ko), (lu32_t*)&sAlo[bf][wb], 16, 0, 0);
        __builtin_amdgcn_global_load_lds((gu32_t*)(pWh+ko), (lu32_t*)&sBhi[bf][wb], 16, 0, 0);
        __builtin_amdgcn_global_load_lds((gu32_t*)(pWl+ko), (lu32_t*)&sBlo[bf][wb], 16, 0, 0);
    };

    int buf = 0;
    stage(0, 0);
    for (int kt=0; kt<nt; ++kt){
        if (kt+1 < nt){
            stage(buf^1, kt+1);
            asm volatile("s_waitcnt vmcnt(4)" ::: "memory");
        } else {
            asm volatile("s_waitcnt vmcnt(0)" ::: "memory");
        }
        __builtin_amdgcn_s_barrier();
        bf16x8 ah[2], al[2], bh[2], bl[2];
        #pragma unroll
        for (int m=0;m<2;m++){
            int row = wr*32 + m*16 + lr;
            uint off = (uint)(row*64 + ((lg ^ ((row>>1)&3))<<4));
            ah[m] = *(const bf16x8*)((const char*)&sAhi[buf][0] + off);
            al[m] = *(const bf16x8*)((const char*)&sAlo[buf][0] + off);
        }
        #pragma unroll
        for (int n=0;n<2;n++){
            int col = wc*32 + n*16 + lr;
            uint off = (uint)(col*64 + ((lg ^ ((col>>1)&3))<<4));
            bh[n] = *(const bf16x8*)((const char*)&sBhi[buf][0] + off);
            bl[n] = *(const bf16x8*)((const char*)&sBlo[buf][0] + off);
        }
        __builtin_amdgcn_s_setprio(1);
        #pragma unroll
        for (int m=0;m<2;m++)
            #pragma unroll
            for (int n=0;n<2;n++){
                acc[m][n] = __builtin_amdgcn_mfma_f32_16x16x32_bf16(ah[m], bh[n], acc[m][n], 0,0,0);
                acc[m][n] = __builtin_amdgcn_mfma_f32_16x16x32_bf16(ah[m], bl[n], acc[m][n], 0,0,0);
                acc[m][n] = __builtin_amdgcn_mfma_f32_16x16x32_bf16(al[m], bh[n], acc[m][n], 0,0,0);
            }
        __builtin_amdgcn_s_setprio(0);
        if (kt+1 < nt) __builtin_amdgcn_s_barrier();
        buf ^= 1;
    }

    if (SPLITK > 1){
        float* Pz = Part + (size_t)bz*M*Nc;
        #pragma unroll
        for (int m=0;m<2;m++){
            #pragma unroll
            for (int n=0;n<2;n++){
                int gcol = bx*64 + wc*32 + n*16 + lr;
                #pragma unroll
                for (int r=0;r<4;r++){
                    int grow = by*64 + wr*32 + m*16 + lg*4 + r;
                    if (grow >= M) continue;
                    Pz[(size_t)grow*Nc + gcol] = acc[m][n][r];
                }
            }
        }
    } else {
        #pragma unroll
        for (int m=0;m<2;m++){
            #pragma unroll
            for (int n=0;n<2;n++){
                int gcol = bx*64 + wc*32 + n*16 + lr;
                float bv = bias[gcol];
                #pragma unroll
                for (int r=0;r<4;r++){
                    int grow = by*64 + wr*32 + m*16 + lg*4 + r;
                    if (grow >= M) continue;
                    int b = grow/ntok; int ni = grow - b*ntok;
                    size_t off = (size_t)(b*LMAX+ni)*Nc + gcol;
                    float v = acc[m][n][r] + bv;
                    if (EPI==1){
                        v = geluf(v);
                        ushort h,lo; split_bf16(v,h,lo);
                        CHi[off]=h; CLo[off]=lo;
                    } else {
                        if (EPI==2) v += R[off];
                        C[off] = v;
                    }
                }
            }
        }
    }
}

// ---- split-K reduce + bias + residual (deterministic fixed order) ----
__global__ __launch_bounds__(256) void reduce_k(const float* __restrict__ P,
        const float* __restrict__ bias, const float* __restrict__ R,
        float* __restrict__ C, int M, int Nc, int S, int ntok)
{
    int idx = blockIdx.x*256 + threadIdx.x;
    int tot = M*(Nc/4);
    if (idx >= tot) return;
    int grow = idx/(Nc/4), c4 = idx - grow*(Nc/4);
    size_t po = (size_t)grow*Nc + c4*4;
    float4 a = *(const float4*)(P + po);
    for (int s=1;s<S;s++){
        float4 v = *(const float4*)(P + (size_t)s*M*Nc + po);
        a.x+=v.x; a.y+=v.y; a.z+=v.z; a.w+=v.w;
    }
    int b = grow/ntok, n = grow - b*ntok;
    size_t off = (size_t)(b*LMAX+n)*Nc + c4*4;
    float4 bv = *(const float4*)(bias + c4*4);
    float4 rv = *(const float4*)(R + off);
    float4 o;
    o.x=a.x+bv.x+rv.x; o.y=a.y+bv.y+rv.y; o.z=a.z+bv.z+rv.z; o.w=a.w+bv.w+rv.w;
    *(float4*)(C + off) = o;
}

// ---------------- block-wide sum over 256 threads ----------------
__device__ __forceinline__ float block_sum256(float v){
    __shared__ float red[4];
    for (int o=32;o>0;o>>=1) v += __shfl_down(v,o,64);
    int t=threadIdx.x;
    if ((t&63)==0) red[t>>6]=v;
    __syncthreads();
    float r = red[0]+red[1]+red[2]+red[3];
    __syncthreads();
    return r;
}

// ---------------- LayerNorm -> split bf16 ----------------
__global__ __launch_bounds__(256) void ln_split(const float* __restrict__ X,
        const float* __restrict__ gam, const float* __restrict__ bet,
        ushort* __restrict__ YHi, ushort* __restrict__ YLo)
{
    int n = blockIdx.x, b = blockIdx.y, t = threadIdx.x;
    const float* xr = X + ((size_t)(b*LMAX+n))*SD;
    size_t ro = ((size_t)(b*LMAX+n))*SD;
    float v0=xr[t], v1=xr[t+256], v2=xr[t+512];
    float mu = block_sum256(v0+v1+v2) * (1.0f/768.0f);
    float d0=v0-mu, d1=v1-mu, d2=v2-mu;
    float var = block_sum256(d0*d0+d1*d1+d2*d2) * (1.0f/768.0f);
    float rs = rsqrtf(var + 1e-6f);
    float y0 = d0*rs*gam[t]     + bet[t];
    float y1 = d1*rs*gam[t+256] + bet[t+256];
    float y2 = d2*rs*gam[t+512] + bet[t+512];
    ushort h,lo;
    split_bf16(y0,h,lo); YHi[ro+t]=h;     YLo[ro+t]=lo;
    split_bf16(y1,h,lo); YHi[ro+t+256]=h; YLo[ro+t+256]=lo;
    split_bf16(y2,h,lo); YHi[ro+t+512]=h; YLo[ro+t+512]=lo;
}

// ---------------- plain LayerNorm (fp32 out) ----------------
__global__ __launch_bounds__(256) void ln_kernel(const float* __restrict__ X,
        const float* __restrict__ gam, const float* __restrict__ bet,
        float* __restrict__ Y)
{
    int n = blockIdx.x, b = blockIdx.y, t = threadIdx.x;
    const float* xr = X + ((size_t)(b*LMAX+n))*SD;
    float* yr = Y + ((size_t)(b*LMAX+n))*SD;
    float v0=xr[t], v1=xr[t+256], v2=xr[t+512];
    float mu = block_sum256(v0+v1+v2) * (1.0f/768.0f);
    float d0=v0-mu, d1=v1-mu, d2=v2-mu;
    float var = block_sum256(d0*d0+d1*d1+d2*d2) * (1.0f/768.0f);
    float rs = rsqrtf(var + 1e-6f);
    yr[t]     = d0*rs*gam[t]     + bet[t];
    yr[t+256] = d1*rs*gam[t+256] + bet[t+256];
    yr[t+512] = d2*rs*gam[t+512] + bet[t+512];
}

// ---------------- tiled attention: one block per (b,h,32-q tile) ----------
__global__ __launch_bounds__(256) void attn_tile(const float* __restrict__ QKV,
        const float* __restrict__ SZ, ushort* __restrict__ OHi,
        ushort* __restrict__ OLo, int N)
{
    const int q0 = blockIdx.x*QBLK;
    const int h = blockIdx.y, b = blockIdx.z, t = threadIdx.x;
    __shared__ float Qs[QBLK][68];
    __shared__ float KVs[KBLK][68];
    __shared__ float Ls[QBLK][200];
    __shared__ float szl[KBLK];
    __shared__ float invs[QBLK];

    {
        int row = t>>3, seg = t&7;
        int q = q0 + row;
        if (q < N){
            const float* src = QKV + ((size_t)(b*LMAX+q))*2304 + h*64 + seg*8;
            *(float4*)&Qs[row][seg*8]   = *(const float4*)src;
            *(float4*)&Qs[row][seg*8+4] = *(const float4*)(src+4);
        } else {
            float4 z = make_float4(0.f,0.f,0.f,0.f);
            *(float4*)&Qs[row][seg*8]   = z;
            *(float4*)&Qs[row][seg*8+4] = z;
        }
    }
    const int tq = t>>3, tk = t&7;
    const int nkt = (N+KBLK-1)/KBLK;

    for (int kt=0; kt<nkt; ++kt){
        int kbase = kt*KBLK;
        __syncthreads();
        {
            int row = t>>2, seg = t&3;
            int ktok = kbase + row;
            float4 a,b4,c,d4;
            if (ktok < N){
                const float* src = QKV + ((size_t)(b*LMAX+ktok))*2304 + 768 + h*64 + seg*16;
                a=*(const float4*)src; b4=*(const float4*)(src+4);
                c=*(const float4*)(src+8); d4=*(const float4*)(src+12);
            } else {
                a=b4=c=d4=make_float4(0.f,0.f,0.f,0.f);
            }
            *(float4*)&KVs[row][seg*16]   =a;
            *(float4*)&KVs[row][seg*16+4] =b4;
            *(float4*)&KVs[row][seg*16+8] =c;
            *(float4*)&KVs[row][seg*16+12]=d4;
            if (t < KBLK){
                int kk2 = kbase + t;
                szl[t] = (kk2<N) ? logf(SZ[b*LMAX+kk2]) : 0.f;
            }
        }
        __syncthreads();
        float acc[8];
        #pragma unroll
        for (int j=0;j<8;j++) acc[j]=0.f;
        #pragma unroll 4
        for (int d4=0; d4<16; ++d4){
            float4 qv = *(const float4*)&Qs[tq][d4*4];
            #pragma unroll
            for (int j=0;j<8;j++){
                float4 kv = *(const float4*)&KVs[tk+8*j][d4*4];
                acc[j] += qv.x*kv.x + qv.y*kv.y + qv.z*kv.z + qv.w*kv.w;
            }
        }
        #pragma unroll
        for (int j=0;j<8;j++){
            int kk = kbase + tk + 8*j;
            if (kk < N) Ls[tq][kk] = acc[j]*0.125f + szl[tk+8*j];
        }
    }
    __syncthreads();

    {
        float m = -INFINITY;
        for (int k=tk;k<N;k+=8) m = fmaxf(m, Ls[tq][k]);
        #pragma unroll
        for (int o=1;o<8;o<<=1) m = fmaxf(m, __shfl_xor(m,o,64));
        float s = 0.f;
        for (int k=tk;k<N;k+=8){
            float p = expf(Ls[tq][k]-m);
            Ls[tq][k]=p; s+=p;
        }
        #pragma unroll
        for (int o=1;o<8;o<<=1) s += __shfl_xor(s,o,64);
        if (tk==0) invs[tq] = 1.0f/s;
    }

    float o0[8];
    #pragma unroll
    for (int i=0;i<8;i++) o0[i]=0.f;
    for (int kt=0; kt<nkt; ++kt){
        int kbase = kt*KBLK;
        __syncthreads();
        {
            int row = t>>2, seg = t&3;
            int ktok = kbase + row;
            float4 a,b4,c,d4;
            if (ktok < N){
                const float* src = QKV + ((size_t)(b*LMAX+ktok))*2304 + 1536 + h*64 + seg*16;
                a=*(const float4*)src; b4=*(const float4*)(src+4);
                c=*(const float4*)(src+8); d4=*(const float4*)(src+12);
            } else {
                a=b4=c=d4=make_float4(0.f,0.f,0.f,0.f);
            }
            *(float4*)&KVs[row][seg*16]   =a;
            *(float4*)&KVs[row][seg*16+4] =b4;
            *(float4*)&KVs[row][seg*16+8] =c;
            *(float4*)&KVs[row][seg*16+12]=d4;
        }
        __syncthreads();
        int kmax = N - kbase; if (kmax > KBLK) kmax = KBLK;
        for (int kk=0; kk<kmax; ++kk){
            float p = Ls[tq][kbase+kk];
            float4 v0 = *(const float4*)&KVs[kk][tk*8];
            float4 v1 = *(const float4*)&KVs[kk][tk*8+4];
            o0[0]+=p*v0.x; o0[1]+=p*v0.y; o0[2]+=p*v0.z; o0[3]+=p*v0.w;
            o0[4]+=p*v1.x; o0[5]+=p*v1.y; o0[6]+=p*v1.z; o0[7]+=p*v1.w;
        }
    }
    int q = q0 + tq;
    if (q < N){
        float inv = invs[tq];
        ushort hh[8], ll[8];
        #pragma unroll
        for (int i=0;i<8;i++){ split_bf16(o0[i]*inv, hh[i], ll[i]); }
        size_t o = ((size_t)(b*LMAX+q))*SD + h*64 + tk*8;
        *(ushort4*)(OHi+o)   = make_ushort4(hh[0],hh[1],hh[2],hh[3]);
        *(ushort4*)(OHi+o+4) = make_ushort4(hh[4],hh[5],hh[6],hh[7]);
        *(ushort4*)(OLo+o)   = make_ushort4(ll[0],ll[1],ll[2],ll[3]);
        *(ushort4*)(OLo+o+4) = make_ushort4(ll[4],ll[5],ll[6],ll[7]);
    }
}

// ---------------- metric = mean_h(k), L2-normalized; 4 tokens/block --------
__global__ __launch_bounds__(256) void metric_k(const float* __restrict__ QKV,
        float* __restrict__ MET, int N)
{
    const int b = blockIdx.y;
    const int sub = threadIdx.x>>6, d = threadIdx.x&63;
    const int n = blockIdx.x*4 + sub;
    if (n >= N) return;
    const float* base = QKV + ((size_t)(b*LMAX+n))*2304 + 768 + d;
    float s=0.f;
    #pragma unroll
    for (int h=0;h<12;h++) s += base[h*64];
    s *= (1.0f/12.0f);
    float sq = s*s;
    for (int o=32;o>0;o>>=1) sq += __shfl_down(sq,o,64);
    float nrm = sqrtf(__shfl(sq,0,64));
    MET[((size_t)(b*LMAX+n))*64 + d] = s/nrm;
}

// ---------------- scores + per-row (max, argmax) ----------------
__global__ __launch_bounds__(128) void scores_k(const float* __restrict__ MET,
        float* __restrict__ NMAX, int* __restrict__ NIDX, int t2)
{
    const int i = blockIdx.x, b = blockIdx.y, t = threadIdx.x;
    __shared__ float ma[64];
    __shared__ float vals[128];
    __shared__ int idxs[128];
    if (t<64) ma[t] = MET[((size_t)(b*LMAX+2*i))*64+t];
    __syncthreads();
    float val = -INFINITY;
    if (t<t2 && i>0){
        const float* mb = MET + ((size_t)(b*LMAX+2*t+1))*64;
        float dot=0.f;
        #pragma unroll 8
        for (int dd=0;dd<64;dd++) dot += ma[dd]*mb[dd];
        val = dot;
    }
    vals[t]=val; idxs[t]=t; __syncthreads();
    for (int s=64;s>0;s>>=1){
        if (t<s){
            float v2=vals[t+s], v1=vals[t]; int i2=idxs[t+s];
            if (v2>v1 || (v2==v1 && i2<idxs[t])){ vals[t]=v2; idxs[t]=i2; }
        }
        __syncthreads();
    }
    if (t==0){ NMAX[b*128+i]=vals[0]; NIDX[b*128+i]=idxs[0]; }
}

// ---------------- plan + token-map update (fused) ----------------
__global__ __launch_bounds__(128) void plan_map(const float* __restrict__ NMAX,
        const int* __restrict__ NIDX, int* __restrict__ SRC, int* __restrict__ DST,
        int* __restrict__ INV, int* __restrict__ MAP,
        int t1, int t2, int r, int mlen)
{
    const int b = blockIdx.x, i = threadIdx.x;
    __shared__ float nm[128];
    __shared__ int issrc[128];
    __shared__ int sstep[208];
    nm[i] = (i<t1) ? NMAX[b*128+i] : INFINITY;
    __syncthreads();
    int rank=0, is=0, ni=0;
    if (i<t1){
        float m = nm[i];
        for (int j=0;j<t1;j++){ float a=nm[j]; if (a>m || (a==m && j<i)) rank++; }
        is = (rank<r) ? 1:0;
        ni = NIDX[b*128+i];
    }
    issrc[i]=is; __syncthreads();
    if (i<t1){
        if (is){ SRC[b*16+rank]=i; DST[b*16+rank]=ni; sstep[2*i] = t1-r+ni; }
        else {
            int cnt=0;
            for (int j=0;j<i;j++) cnt += 1-issrc[j];
            sstep[2*i]=cnt;
            INV[b*LMAX+cnt]=2*i;
        }
    }
    if (i<t2){ sstep[2*i+1]=t1-r+i; INV[b*LMAX+(t1-r)+i]=2*i+1; }
    __syncthreads();
    for (int idx=i; idx<mlen; idx+=128)
        MAP[b*LMAX+idx] = sstep[MAP[b*LMAX+idx]];
}

// ---------------- fused merge ----------------
__global__ __launch_bounds__(256) void merge_fused(const float* __restrict__ X,
        const float* __restrict__ SZ, const int* __restrict__ INV,
        const int* __restrict__ SRC, const int* __restrict__ DST,
        float* __restrict__ XO, float* __restrict__ SZO, int t1, int r)
{
    int p = blockIdx.x, b = blockIdx.y, t = threadIdx.x;
    int base = t1 - r;
    float acc0, acc1, acc2, snew;
    if (p < base){
        int tok = INV[b*LMAX+p];
        float s = SZ[b*LMAX+tok];
        const float* xr = X + (size_t)(b*LMAX+tok)*SD;
        acc0=xr[t]*s; acc1=xr[t+256]*s; acc2=xr[t+512]*s; snew=s;
    } else {
        int d = p - base;
        int tok = 2*d+1;
        float s = SZ[b*LMAX+tok];
        const float* xr = X + (size_t)(b*LMAX+tok)*SD;
        acc0=xr[t]*s; acc1=xr[t+256]*s; acc2=xr[t+512]*s; snew=s;
        for (int k=0;k<r;k++){
            if (DST[b*16+k]==d){
                int st = 2*SRC[b*16+k];
                float ss = SZ[b*LMAX+st];
                const float* xs = X + (size_t)(b*LMAX+st)*SD;
                acc0+=xs[t]*ss; acc1+=xs[t+256]*ss; acc2+=xs[t+512]*ss; snew+=ss;
            }
        }
    }
    float inv = 1.0f/snew;
    float* o = XO + (size_t)(b*LMAX+p)*SD;
    o[t]=acc0*inv; o[t+256]=acc1*inv; o[t+512]=acc2*inv;
    if (t==0) SZO[b*LMAX+p]=snew;
}

// ---------------- patchify (split output) ----------------
__global__ void patchify(const float* __restrict__ X, ushort* __restrict__ PHi,
        ushort* __restrict__ PLo)
{
    size_t i = (size_t)blockIdx.x*256 + threadIdx.x;
    if (i >= (size_t)NB*196*768) return;
    int f = i % 768; size_t q = i/768; int p = q % 196; int b = q/196;
    int c = f >> 8, py = (f>>4)&15, px = f&15;
    int gy = p/14, gx = p - gy*14;
    float v = X[(((size_t)b*3 + c)*224 + gy*16+py)*224 + gx*16+px];
    ushort h,l; split_bf16(v,h,l);
    size_t o = ((size_t)(b*LMAX+p))*768 + f;
    PHi[o]=h; PLo[o]=l;
}

__global__ void assemble(const float* __restrict__ T, const float* __restrict__ cls,
        const float* __restrict__ pos, float* __restrict__ Xo)
{
    size_t i = (size_t)blockIdx.x*256 + threadIdx.x;
    if (i >= (size_t)NB*LMAX*768) return;
    int d = i % 768; size_t q = i/768; int n = q % LMAX; int b = q/LMAX;
    float v = (n==0) ? cls[d] : T[((size_t)(b*LMAX+n-1))*768+d];
    Xo[((size_t)(b*LMAX+n))*768+d] = v + pos[n*768+d];
}

__global__ void init_state(float* __restrict__ SZ, int* __restrict__ TMAP, int* __restrict__ SMAP)
{
    int i = blockIdx.x*256+threadIdx.x;
    if (i >= NB*LMAX) return;
    SZ[i]=1.0f;
    int n=i%LMAX;
    TMAP[i]=n;
    if (n<149) SMAP[i]=n;
}

// ---------------- head ----------------
__global__ void head_k(const float* __restrict__ XG, const int* __restrict__ SMAP,
        const int* __restrict__ TMAP, const float* __restrict__ HW,
        const float* __restrict__ HB, float* __restrict__ OUT)
{
    int t = threadIdx.x;
    if (t>=80) return;
    int b=t/10, o=t-b*10;
    int row = SMAP[b*LMAX + TMAP[b*LMAX]];
    const float* xr = XG + ((size_t)(b*LMAX+row))*SD;
    float acc = HB[o];
    for (int d=0;d<SD;d++) acc += xr[d]*HW[d*10+o];
    OUT[b*10+o]=acc;
}

extern "C" void kernel_launch(void* const* d_in, const int* in_sizes, int n_in,
                              void* d_out, int out_size, void* d_ws, size_t ws_size,
                              hipStream_t stream)
{
    const float* x_in    = (const float*)d_in[0];
    const float* patch_w = (const float*)d_in[1];
    const float* patch_b = (const float*)d_in[2];
    const float* cls     = (const float*)d_in[3];
    const float* pos     = (const float*)d_in[4];
    const float* l_ng    = (const float*)d_in[5];
    const float* l_nb    = (const float*)d_in[6];
    const float* g_ng    = (const float*)d_in[7];
    const float* g_nb    = (const float*)d_in[8];
    const float* head_w  = (const float*)d_in[9];
    const float* head_b  = (const float*)d_in[10];
    const float* L[12];  for (int i=0;i<12;i++) L[i]  = (const float*)d_in[11+i];
    const float* Gp[12]; for (int i=0;i<12;i++) Gp[i] = (const float*)d_in[23+i];
    float* out = (float*)d_out;

    float* fp = (float*)d_ws;
    float* xA      = fp; fp += (size_t)NB*LMAX*SD;
    float* xB      = fp; fp += (size_t)NB*LMAX*SD;
    float* qkvbuf  = fp; fp += (size_t)NB*LMAX*2304;
    float* metricbuf=fp; fp += (size_t)NB*LMAX*64;
    float* partbuf = fp; fp += (size_t)4*NB*LMAX*SD;   // split-K partials
    float* szA     = fp; fp += NB*LMAX;
    float* szB     = fp; fp += NB*LMAX;
    float* nodemax = fp; fp += NB*128;
    int* ip = (int*)fp;
    int* tmap    = ip; ip += NB*LMAX;
    int* smap    = ip; ip += NB*LMAX;
    int* invrow  = ip; ip += NB*LMAX;
    int* nodeidx = ip; ip += NB*128;
    int* srcs    = ip; ip += NB*16;
    int* dsts    = ip; ip += NB*16;
    uintptr_t up = ((uintptr_t)ip + 15) & ~(uintptr_t)15;
    ushort* sp = (ushort*)up;
    ushort* lnHi = sp; sp += (size_t)NB*LMAX*SD;
    ushort* lnLo = sp; sp += (size_t)NB*LMAX*SD;
    ushort* oHi  = sp; sp += (size_t)NB*LMAX*SD;
    ushort* oLo  = sp; sp += (size_t)NB*LMAX*SD;
    ushort* hHi  = sp; sp += (size_t)NB*LMAX*3072;
    ushort* hLo  = sp; sp += (size_t)NB*LMAX*3072;
    ushort* pHi  = sp; sp += (size_t)NB*LMAX*SD;
    ushort* pLo  = sp; sp += (size_t)NB*LMAX*SD;
    ushort* patchHi = sp; sp += (size_t)768*768;
    ushort* patchLo = sp; sp += (size_t)768*768;
    ushort* qkvHi = sp; sp += (size_t)4*768*2304;
    ushort* qkvLo = sp; sp += (size_t)4*768*2304;
    ushort* projHi= sp; sp += (size_t)4*768*768;
    ushort* projLo= sp; sp += (size_t)4*768*768;
    ushort* fc1Hi = sp; sp += (size_t)4*768*3072;
    ushort* fc1Lo = sp; sp += (size_t)4*768*3072;
    ushort* fc2Hi = sp; sp += (size_t)4*3072*768;
    ushort* fc2Lo = sp; sp += (size_t)4*3072*768;

    float *xc = xA, *xn = xB, *szc = szA, *szn = szB;

    auto conv_chunk = [&](const float* qw, const float* pw, const float* f1w,
                          const float* f2w, int nz)
    {
        wconv<<<dim3(2304/32,768/32,nz),256,0,stream>>>(qw, qkvHi, qkvLo, SD, 2304);
        wconv<<<dim3(768/32,768/32,nz),256,0,stream>>>(pw, projHi, projLo, SD, SD);
        wconv<<<dim3(3072/32,768/32,nz),256,0,stream>>>(f1w, fc1Hi, fc1Lo, SD, 3072);
        wconv<<<dim3(768/32,3072/32,nz),256,0,stream>>>(f2w, fc2Hi, fc2Lo, 3072, SD);
    };

    auto run_block = [&](const float* ln1g, const float* ln1b, const float* qb,
                         const float* pb, const float* ln2g, const float* ln2b,
                         const float* f1b, const float* f2b,
                         int slot, int N, int r, int* mp, int mlen)
    {
        int M = NB*N;
        int Mt = (M+63)/64;
        const ushort* qH = qkvHi + (size_t)slot*768*2304;
        const ushort* qL = qkvLo + (size_t)slot*768*2304;
        const ushort* pH = projHi + (size_t)slot*768*768;
        const ushort* pL = projLo + (size_t)slot*768*768;
        const ushort* f1H = fc1Hi + (size_t)slot*768*3072;
        const ushort* f1L = fc1Lo + (size_t)slot*768*3072;
        const ushort* f2H = fc2Hi + (size_t)slot*3072*768;
        const ushort* f2L = fc2Lo + (size_t)slot*3072*768;

        ln_split<<<dim3(N,NB),256,0,stream>>>(xc, ln1g, ln1b, lnHi, lnLo);
        gemm_mfma<0,1><<<36*Mt,256,0,stream>>>(lnHi, lnLo, qH, qL, qb, nullptr, qkvbuf, nullptr, nullptr, nullptr, M, 2304, SD, N, 36);
        attn_tile<<<dim3((N+QBLK-1)/QBLK,NHEAD,NB),256,0,stream>>>(qkvbuf, szc, oHi, oLo, N);
        metric_k<<<dim3((N+3)/4,NB),256,0,stream>>>(qkvbuf, metricbuf, N);
        // proj: split-K=4 partials + deterministic reduce (bias+residual)
        gemm_mfma<0,4><<<12*Mt*4,256,0,stream>>>(oHi, oLo, pH, pL, nullptr, nullptr, nullptr, nullptr, nullptr, partbuf, M, SD, SD, N, 12);
        reduce_k<<<(M*(SD/4)+255)/256,256,0,stream>>>(partbuf, pb, xc, xc, M, SD, 4, N);
        int t1=(N+1)/2, t2=N/2, Nn=N-r;
        scores_k<<<dim3(t1,NB),128,0,stream>>>(metricbuf, nodemax, nodeidx, t2);
        plan_map<<<NB,128,0,stream>>>(nodemax, nodeidx, srcs, dsts, invrow, mp, t1, t2, r, mlen);
        merge_fused<<<dim3(Nn,NB),256,0,stream>>>(xc, szc, invrow, srcs, dsts, xn, szn, t1, r);
        int M2 = NB*Nn;
        int M2t = (M2+63)/64;
        ln_split<<<dim3(Nn,NB),256,0,stream>>>(xn, ln2g, ln2b, lnHi, lnLo);
        gemm_mfma<1,1><<<48*M2t,256,0,stream>>>(lnHi, lnLo, f1H, f1L, f1b, nullptr, nullptr, hHi, hLo, nullptr, M2, 3072, SD, Nn, 48);
        // fc2: split-K=4 partials + deterministic reduce (bias+residual)
        gemm_mfma<0,4><<<12*M2t*4,256,0,stream>>>(hHi, hLo, f2H, f2L, nullptr, nullptr, nullptr, nullptr, nullptr, partbuf, M2, SD, 3072, Nn, 12);
        reduce_k<<<(M2*(SD/4)+255)/256,256,0,stream>>>(partbuf, f2b, xn, xn, M2, SD, 4, Nn);
        float* tf; tf=xc; xc=xn; xn=tf; tf=szc; szc=szn; szn=tf;
    };

    // ---- patch embedding + token assembly ----
    {
        int tot = NB*196*768;
        patchify<<<(tot+255)/256,256,0,stream>>>(x_in, pHi, pLo);
        wconv<<<dim3(768/32,768/32,1),256,0,stream>>>(patch_w, patchHi, patchLo, SD, SD);
        gemm_mfma<0,1><<<12*((NB*196+63)/64),256,0,stream>>>(pHi, pLo, patchHi, patchLo, patch_b, nullptr, qkvbuf, nullptr, nullptr, nullptr, NB*196, SD, SD, 196, 12);
        int tot2 = NB*LMAX*768;
        assemble<<<(tot2+255)/256,256,0,stream>>>(qkvbuf, cls, pos, xc);
        init_state<<<(NB*LMAX+255)/256,256,0,stream>>>(szc, tmap, smap);
    }

    // ---- local encoder: 4 blocks, r=12 ----
    conv_chunk(L[2], L[4], L[8], L[10], 4);
    int N = 197;
    for (int i=0;i<4;i++){
        run_block(L[0]+i*768, L[1]+i*768, L[3]+(size_t)i*2304,
                  L[5]+(size_t)i*768, L[6]+i*768, L[7]+i*768,
                  L[9]+(size_t)i*3072, L[11]+(size_t)i*768,
                  i, N, 12, tmap, 197);
        N -= 12;
    }
    ln_kernel<<<dim3(N,NB),256,0,stream>>>(xc, l_ng, l_nb, xc);

    // ---- global encoder: 12 blocks, r=8, weight chunks of 4 ----
    for (int c=0;c<3;c++){
        conv_chunk(Gp[2]+(size_t)(4*c)*768*2304, Gp[4]+(size_t)(4*c)*768*768,
                   Gp[8]+(size_t)(4*c)*768*3072, Gp[10]+(size_t)(4*c)*3072*768, 4);
        for (int j=0;j<4;j++){
            int i = 4*c+j;
            run_block(Gp[0]+i*768, Gp[1]+i*768, Gp[3]+(size_t)i*2304,
                      Gp[5]+(size_t)i*768, Gp[6]+i*768, Gp[7]+i*768,
                      Gp[9]+(size_t)i*3072, Gp[11]+(size_t)i*768,
                      j, N, 8, smap, 149);
            N -= 8;
        }
    }
    ln_kernel<<<dim3(N,NB),256,0,stream>>>(xc, g_ng, g_nb, qkvbuf);
    head_k<<<1,128,0,stream>>>(qkvbuf, smap, tmap, head_w, head_b, out);
}

// Round 13
// 2740.177 us; speedup vs baseline: 1.1849x; 1.1849x over previous
//
#include <hip/hip_runtime.h>
#include <math.h>

#define NB 8
#define SD 768
#define NHEAD 12
#define LMAX 197
#define QBLK 32
#define KBLK 64

typedef __attribute__((ext_vector_type(8))) short bf16x8;
typedef __attribute__((ext_vector_type(4))) float f32x4;
typedef const __attribute__((address_space(1))) unsigned int gu32_t;
typedef __attribute__((address_space(3))) unsigned int lu32_t;

static __device__ __forceinline__ float geluf(float x){
    return 0.5f*x*(1.0f+erff(x*0.70710678118654752440f));
}

static __device__ __forceinline__ void split_bf16(float v, ushort& h, ushort& l){
    uint u = __float_as_uint(v);
    uint hb = (u + 0x7FFFu + ((u>>16)&1u)) >> 16;
    h = (ushort)hb;
    float rem = v - __uint_as_float(hb<<16);
    uint u2 = __float_as_uint(rem);
    l = (ushort)((u2 + 0x7FFFu + ((u2>>16)&1u)) >> 16);
}

// ---- weight convert+transpose (batched): W[z][K][Nc] fp32 -> Hi/Lo[z][Nc][K]
__global__ __launch_bounds__(256) void wconv(const float* __restrict__ W,
        ushort* __restrict__ Hi, ushort* __restrict__ Lo, int K, int Nc)
{
    __shared__ float tile[32][33];
    int z = blockIdx.z;
    const float* Wz = W + (size_t)z*K*Nc;
    ushort* Hz = Hi + (size_t)z*Nc*K;
    ushort* Lz = Lo + (size_t)z*Nc*K;
    int n0 = blockIdx.x*32, k0 = blockIdx.y*32;
    int tx = threadIdx.x&31, ty = threadIdx.x>>5;
    #pragma unroll
    for (int i=0;i<32;i+=8) tile[ty+i][tx] = Wz[(size_t)(k0+ty+i)*Nc + n0+tx];
    __syncthreads();
    #pragma unroll
    for (int i=0;i<32;i+=8){
        float v = tile[tx][ty+i];
        ushort h,l; split_bf16(v,h,l);
        size_t o = (size_t)(n0+ty+i)*K + k0+tx;
        Hz[o]=h; Lz[o]=l;
    }
}

// ---- split-bf16 MFMA GEMM: BK=32, double-buffered 32KB LDS via
// global_load_lds, counted vmcnt(4). 1D grid with bijective XCD swizzle.
// Bank-conflict fix (both-sides swizzle): LDS[row][p] holds global 16B chunk
// p ^ ((row>>1)&3). NOTE: no setprio (m190: hurts lockstep GEMM, verified
// round 12 −23% on split-K dispatches); both barriers kept.
template<int EPI, int SPLITK>
__global__ __launch_bounds__(256) void gemm_mfma(const ushort* __restrict__ AHi,
        const ushort* __restrict__ ALo, const ushort* __restrict__ WHi,
        const ushort* __restrict__ WLo, const float* __restrict__ bias,
        const float* __restrict__ R, float* __restrict__ C,
        ushort* __restrict__ CHi, ushort* __restrict__ CLo,
        float* __restrict__ Part, int M, int Nc, int K, int ntok, int gx)
{
    __shared__ __align__(16) ushort sAhi[2][2048], sAlo[2][2048];
    __shared__ __align__(16) ushort sBhi[2][2048], sBlo[2][2048];
    const int t = threadIdx.x;
    const int nwg = gridDim.x;
    const int qc = nwg>>3, rc = nwg&7;
    const int xcd = blockIdx.x & 7, jj = blockIdx.x >> 3;
    const int wid = (xcd<rc ? xcd*(qc+1) : rc*(qc+1)+(xcd-rc)*qc) + jj;
    const int bx = wid % gx;
    const int t2 = wid / gx;
    const int gy = nwg/(gx*SPLITK);
    const int by = t2 % gy;
    const int bz = t2 / gy;

    const int w = t>>6, l = t&63, lr = l&15, lg = l>>4;
    const int wr = w>>1, wc = w&1;

    const int Ks = K/SPLITK;
    const int kbeg = bz*Ks;
    const int nt = Ks/32;

    const int srow = t>>2;
    const uint schunk = (uint)((((t&3) ^ ((t>>3)&3)))*16);
    int ar = by*64 + srow; if (ar >= M) ar = M-1;
    int ab_ = ar/ntok; int an_ = ar - ab_*ntok;
    size_t aoff = ((size_t)(ab_*LMAX+an_)*K + kbeg)*2 + schunk;
    size_t woff = ((size_t)(bx*64+srow)*K + kbeg)*2 + schunk;
    const char* pAh = (const char*)AHi + aoff;
    const char* pAl = (const char*)ALo + aoff;
    const char* pWh = (const char*)WHi + woff;
    const char* pWl = (const char*)WLo + woff;

    f32x4 acc[2][2];
    #pragma unroll
    for (int i=0;i<2;i++)
        #pragma unroll
        for (int j=0;j<2;j++) acc[i][j] = (f32x4){0.f,0.f,0.f,0.f};

    const uint wb = (uint)(w*512);

    auto stage = [&](int bf, int kt){
        size_t ko = (size_t)kt*64;
        __builtin_amdgcn_global_load_lds((gu32_t*)(pAh+ko), (lu32_t*)&sAhi[bf][wb], 16, 0, 0);
        __builtin_amdgcn_global_load_lds((gu32_t*)(pAl+ko), (lu32_t*)&sAlo[bf][wb], 16, 0, 0);
        __builtin_amdgcn_global_load_lds((gu32_t*)(pWh+ko), (lu32_t*)&sBhi[bf][wb], 16, 0, 0);
        __builtin_amdgcn_global_load_lds((gu32_t*)(pWl+ko), (lu32_t*)&sBlo[bf][wb], 16, 0, 0);
    };

    int buf = 0;
    stage(0, 0);
    for (int kt=0; kt<nt; ++kt){
        if (kt+1 < nt){
            stage(buf^1, kt+1);
            asm volatile("s_waitcnt vmcnt(4)" ::: "memory");
        } else {
            asm volatile("s_waitcnt vmcnt(0)" ::: "memory");
        }
        __builtin_amdgcn_s_barrier();
        bf16x8 ah[2], al[2], bh[2], bl[2];
        #pragma unroll
        for (int m=0;m<2;m++){
            int row = wr*32 + m*16 + lr;
            uint off = (uint)(row*64 + ((lg ^ ((row>>1)&3))<<4));
            ah[m] = *(const bf16x8*)((const char*)&sAhi[buf][0] + off);
            al[m] = *(const bf16x8*)((const char*)&sAlo[buf][0] + off);
        }
        #pragma unroll
        for (int n=0;n<2;n++){
            int col = wc*32 + n*16 + lr;
            uint off = (uint)(col*64 + ((lg ^ ((col>>1)&3))<<4));
            bh[n] = *(const bf16x8*)((const char*)&sBhi[buf][0] + off);
            bl[n] = *(const bf16x8*)((const char*)&sBlo[buf][0] + off);
        }
        #pragma unroll
        for (int m=0;m<2;m++)
            #pragma unroll
            for (int n=0;n<2;n++){
                acc[m][n] = __builtin_amdgcn_mfma_f32_16x16x32_bf16(ah[m], bh[n], acc[m][n], 0,0,0);
                acc[m][n] = __builtin_amdgcn_mfma_f32_16x16x32_bf16(ah[m], bl[n], acc[m][n], 0,0,0);
                acc[m][n] = __builtin_amdgcn_mfma_f32_16x16x32_bf16(al[m], bh[n], acc[m][n], 0,0,0);
            }
        __builtin_amdgcn_s_barrier();
        buf ^= 1;
    }

    if (SPLITK > 1){
        float* Pz = Part + (size_t)bz*M*Nc;
        #pragma unroll
        for (int m=0;m<2;m++){
            #pragma unroll
            for (int n=0;n<2;n++){
                int gcol = bx*64 + wc*32 + n*16 + lr;
                #pragma unroll
                for (int r=0;r<4;r++){
                    int grow = by*64 + wr*32 + m*16 + lg*4 + r;
                    if (grow >= M) continue;
                    Pz[(size_t)grow*Nc + gcol] = acc[m][n][r];
                }
            }
        }
    } else {
        #pragma unroll
        for (int m=0;m<2;m++){
            #pragma unroll
            for (int n=0;n<2;n++){
                int gcol = bx*64 + wc*32 + n*16 + lr;
                float bv = bias[gcol];
                #pragma unroll
                for (int r=0;r<4;r++){
                    int grow = by*64 + wr*32 + m*16 + lg*4 + r;
                    if (grow >= M) continue;
                    int b = grow/ntok; int ni = grow - b*ntok;
                    size_t off = (size_t)(b*LMAX+ni)*Nc + gcol;
                    float v = acc[m][n][r] + bv;
                    if (EPI==1){
                        v = geluf(v);
                        ushort h,lo; split_bf16(v,h,lo);
                        CHi[off]=h; CLo[off]=lo;
                    } else {
                        if (EPI==2) v += R[off];
                        C[off] = v;
                    }
                }
            }
        }
    }
}

// ---- split-K reduce + bias + residual (deterministic fixed order) ----
__global__ __launch_bounds__(256) void reduce_k(const float* __restrict__ P,
        const float* __restrict__ bias, const float* __restrict__ R,
        float* __restrict__ C, int M, int Nc, int S, int ntok)
{
    int idx = blockIdx.x*256 + threadIdx.x;
    int tot = M*(Nc/4);
    if (idx >= tot) return;
    int grow = idx/(Nc/4), c4 = idx - grow*(Nc/4);
    size_t po = (size_t)grow*Nc + c4*4;
    float4 a = *(const float4*)(P + po);
    for (int s=1;s<S;s++){
        float4 v = *(const float4*)(P + (size_t)s*M*Nc + po);
        a.x+=v.x; a.y+=v.y; a.z+=v.z; a.w+=v.w;
    }
    int b = grow/ntok, n = grow - b*ntok;
    size_t off = (size_t)(b*LMAX+n)*Nc + c4*4;
    float4 bv = *(const float4*)(bias + c4*4);
    float4 rv = *(const float4*)(R + off);
    float4 o;
    o.x=a.x+bv.x+rv.x; o.y=a.y+bv.y+rv.y; o.z=a.z+bv.z+rv.z; o.w=a.w+bv.w+rv.w;
    *(float4*)(C + off) = o;
}

// ---------------- block-wide sum over 256 threads ----------------
__device__ __forceinline__ float block_sum256(float v){
    __shared__ float red[4];
    for (int o=32;o>0;o>>=1) v += __shfl_down(v,o,64);
    int t=threadIdx.x;
    if ((t&63)==0) red[t>>6]=v;
    __syncthreads();
    float r = red[0]+red[1]+red[2]+red[3];
    __syncthreads();
    return r;
}

// ---------------- LayerNorm -> split bf16 ----------------
__global__ __launch_bounds__(256) void ln_split(const float* __restrict__ X,
        const float* __restrict__ gam, const float* __restrict__ bet,
        ushort* __restrict__ YHi, ushort* __restrict__ YLo)
{
    int n = blockIdx.x, b = blockIdx.y, t = threadIdx.x;
    const float* xr = X + ((size_t)(b*LMAX+n))*SD;
    size_t ro = ((size_t)(b*LMAX+n))*SD;
    float v0=xr[t], v1=xr[t+256], v2=xr[t+512];
    float mu = block_sum256(v0+v1+v2) * (1.0f/768.0f);
    float d0=v0-mu, d1=v1-mu, d2=v2-mu;
    float var = block_sum256(d0*d0+d1*d1+d2*d2) * (1.0f/768.0f);
    float rs = rsqrtf(var + 1e-6f);
    float y0 = d0*rs*gam[t]     + bet[t];
    float y1 = d1*rs*gam[t+256] + bet[t+256];
    float y2 = d2*rs*gam[t+512] + bet[t+512];
    ushort h,lo;
    split_bf16(y0,h,lo); YHi[ro+t]=h;     YLo[ro+t]=lo;
    split_bf16(y1,h,lo); YHi[ro+t+256]=h; YLo[ro+t+256]=lo;
    split_bf16(y2,h,lo); YHi[ro+t+512]=h; YLo[ro+t+512]=lo;
}

// ---------------- plain LayerNorm (fp32 out) ----------------
__global__ __launch_bounds__(256) void ln_kernel(const float* __restrict__ X,
        const float* __restrict__ gam, const float* __restrict__ bet,
        float* __restrict__ Y)
{
    int n = blockIdx.x, b = blockIdx.y, t = threadIdx.x;
    const float* xr = X + ((size_t)(b*LMAX+n))*SD;
    float* yr = Y + ((size_t)(b*LMAX+n))*SD;
    float v0=xr[t], v1=xr[t+256], v2=xr[t+512];
    float mu = block_sum256(v0+v1+v2) * (1.0f/768.0f);
    float d0=v0-mu, d1=v1-mu, d2=v2-mu;
    float var = block_sum256(d0*d0+d1*d1+d2*d2) * (1.0f/768.0f);
    float rs = rsqrtf(var + 1e-6f);
    yr[t]     = d0*rs*gam[t]     + bet[t];
    yr[t+256] = d1*rs*gam[t+256] + bet[t+256];
    yr[t+512] = d2*rs*gam[t+512] + bet[t+512];
}

// ---------------- tiled attention: one block per (b,h,32-q tile) ----------
__global__ __launch_bounds__(256) void attn_tile(const float* __restrict__ QKV,
        const float* __restrict__ SZ, ushort* __restrict__ OHi,
        ushort* __restrict__ OLo, int N)
{
    const int q0 = blockIdx.x*QBLK;
    const int h = blockIdx.y, b = blockIdx.z, t = threadIdx.x;
    __shared__ float Qs[QBLK][68];
    __shared__ float KVs[KBLK][68];
    __shared__ float Ls[QBLK][200];
    __shared__ float szl[KBLK];
    __shared__ float invs[QBLK];

    {
        int row = t>>3, seg = t&7;
        int q = q0 + row;
        if (q < N){
            const float* src = QKV + ((size_t)(b*LMAX+q))*2304 + h*64 + seg*8;
            *(float4*)&Qs[row][seg*8]   = *(const float4*)src;
            *(float4*)&Qs[row][seg*8+4] = *(const float4*)(src+4);
        } else {
            float4 z = make_float4(0.f,0.f,0.f,0.f);
            *(float4*)&Qs[row][seg*8]   = z;
            *(float4*)&Qs[row][seg*8+4] = z;
        }
    }
    const int tq = t>>3, tk = t&7;
    const int nkt = (N+KBLK-1)/KBLK;

    for (int kt=0; kt<nkt; ++kt){
        int kbase = kt*KBLK;
        __syncthreads();
        {
            int row = t>>2, seg = t&3;
            int ktok = kbase + row;
            float4 a,b4,c,d4;
            if (ktok < N){
                const float* src = QKV + ((size_t)(b*LMAX+ktok))*2304 + 768 + h*64 + seg*16;
                a=*(const float4*)src; b4=*(const float4*)(src+4);
                c=*(const float4*)(src+8); d4=*(const float4*)(src+12);
            } else {
                a=b4=c=d4=make_float4(0.f,0.f,0.f,0.f);
            }
            *(float4*)&KVs[row][seg*16]   =a;
            *(float4*)&KVs[row][seg*16+4] =b4;
            *(float4*)&KVs[row][seg*16+8] =c;
            *(float4*)&KVs[row][seg*16+12]=d4;
            if (t < KBLK){
                int kk2 = kbase + t;
                szl[t] = (kk2<N) ? logf(SZ[b*LMAX+kk2]) : 0.f;
            }
        }
        __syncthreads();
        float acc[8];
        #pragma unroll
        for (int j=0;j<8;j++) acc[j]=0.f;
        #pragma unroll 4
        for (int d4=0; d4<16; ++d4){
            float4 qv = *(const float4*)&Qs[tq][d4*4];
            #pragma unroll
            for (int j=0;j<8;j++){
                float4 kv = *(const float4*)&KVs[tk+8*j][d4*4];
                acc[j] += qv.x*kv.x + qv.y*kv.y + qv.z*kv.z + qv.w*kv.w;
            }
        }
        #pragma unroll
        for (int j=0;j<8;j++){
            int kk = kbase + tk + 8*j;
            if (kk < N) Ls[tq][kk] = acc[j]*0.125f + szl[tk+8*j];
        }
    }
    __syncthreads();

    {
        float m = -INFINITY;
        for (int k=tk;k<N;k+=8) m = fmaxf(m, Ls[tq][k]);
        #pragma unroll
        for (int o=1;o<8;o<<=1) m = fmaxf(m, __shfl_xor(m,o,64));
        float s = 0.f;
        for (int k=tk;k<N;k+=8){
            float p = expf(Ls[tq][k]-m);
            Ls[tq][k]=p; s+=p;
        }
        #pragma unroll
        for (int o=1;o<8;o<<=1) s += __shfl_xor(s,o,64);
        if (tk==0) invs[tq] = 1.0f/s;
    }

    float o0[8];
    #pragma unroll
    for (int i=0;i<8;i++) o0[i]=0.f;
    for (int kt=0; kt<nkt; ++kt){
        int kbase = kt*KBLK;
        __syncthreads();
        {
            int row = t>>2, seg = t&3;
            int ktok = kbase + row;
            float4 a,b4,c,d4;
            if (ktok < N){
                const float* src = QKV + ((size_t)(b*LMAX+ktok))*2304 + 1536 + h*64 + seg*16;
                a=*(const float4*)src; b4=*(const float4*)(src+4);
                c=*(const float4*)(src+8); d4=*(const float4*)(src+12);
            } else {
                a=b4=c=d4=make_float4(0.f,0.f,0.f,0.f);
            }
            *(float4*)&KVs[row][seg*16]   =a;
            *(float4*)&KVs[row][seg*16+4] =b4;
            *(float4*)&KVs[row][seg*16+8] =c;
            *(float4*)&KVs[row][seg*16+12]=d4;
        }
        __syncthreads();
        int kmax = N - kbase; if (kmax > KBLK) kmax = KBLK;
        for (int kk=0; kk<kmax; ++kk){
            float p = Ls[tq][kbase+kk];
            float4 v0 = *(const float4*)&KVs[kk][tk*8];
            float4 v1 = *(const float4*)&KVs[kk][tk*8+4];
            o0[0]+=p*v0.x; o0[1]+=p*v0.y; o0[2]+=p*v0.z; o0[3]+=p*v0.w;
            o0[4]+=p*v1.x; o0[5]+=p*v1.y; o0[6]+=p*v1.z; o0[7]+=p*v1.w;
        }
    }
    int q = q0 + tq;
    if (q < N){
        float inv = invs[tq];
        ushort hh[8], ll[8];
        #pragma unroll
        for (int i=0;i<8;i++){ split_bf16(o0[i]*inv, hh[i], ll[i]); }
        size_t o = ((size_t)(b*LMAX+q))*SD + h*64 + tk*8;
        *(ushort4*)(OHi+o)   = make_ushort4(hh[0],hh[1],hh[2],hh[3]);
        *(ushort4*)(OHi+o+4) = make_ushort4(hh[4],hh[5],hh[6],hh[7]);
        *(ushort4*)(OLo+o)   = make_ushort4(ll[0],ll[1],ll[2],ll[3]);
        *(ushort4*)(OLo+o+4) = make_ushort4(ll[4],ll[5],ll[6],ll[7]);
    }
}

// ---------------- metric = mean_h(k), L2-normalized; 4 tokens/block --------
__global__ __launch_bounds__(256) void metric_k(const float* __restrict__ QKV,
        float* __restrict__ MET, int N)
{
    const int b = blockIdx.y;
    const int sub = threadIdx.x>>6, d = threadIdx.x&63;
    const int n = blockIdx.x*4 + sub;
    if (n >= N) return;
    const float* base = QKV + ((size_t)(b*LMAX+n))*2304 + 768 + d;
    float s=0.f;
    #pragma unroll
    for (int h=0;h<12;h++) s += base[h*64];
    s *= (1.0f/12.0f);
    float sq = s*s;
    for (int o=32;o>0;o>>=1) sq += __shfl_down(sq,o,64);
    float nrm = sqrtf(__shfl(sq,0,64));
    MET[((size_t)(b*LMAX+n))*64 + d] = s/nrm;
}

// ---------------- scores + per-row (max, argmax) ----------------
__global__ __launch_bounds__(128) void scores_k(const float* __restrict__ MET,
        float* __restrict__ NMAX, int* __restrict__ NIDX, int t2)
{
    const int i = blockIdx.x, b = blockIdx.y, t = threadIdx.x;
    __shared__ float ma[64];
    __shared__ float vals[128];
    __shared__ int idxs[128];
    if (t<64) ma[t] = MET[((size_t)(b*LMAX+2*i))*64+t];
    __syncthreads();
    float val = -INFINITY;
    if (t<t2 && i>0){
        const float* mb = MET + ((size_t)(b*LMAX+2*t+1))*64;
        float dot=0.f;
        #pragma unroll 8
        for (int dd=0;dd<64;dd++) dot += ma[dd]*mb[dd];
        val = dot;
    }
    vals[t]=val; idxs[t]=t; __syncthreads();
    for (int s=64;s>0;s>>=1){
        if (t<s){
            float v2=vals[t+s], v1=vals[t]; int i2=idxs[t+s];
            if (v2>v1 || (v2==v1 && i2<idxs[t])){ vals[t]=v2; idxs[t]=i2; }
        }
        __syncthreads();
    }
    if (t==0){ NMAX[b*128+i]=vals[0]; NIDX[b*128+i]=idxs[0]; }
}

// ---------------- plan ----------------
__global__ __launch_bounds__(128) void plan_k(const float* __restrict__ NMAX,
        const int* __restrict__ NIDX, int* __restrict__ SRC, int* __restrict__ DST,
        int* __restrict__ STEP, int* __restrict__ INV, int t1, int t2, int r)
{
    const int b = blockIdx.x, i = threadIdx.x;
    __shared__ float nm[128];
    __shared__ int issrc[128];
    nm[i] = (i<t1) ? NMAX[b*128+i] : INFINITY;
    __syncthreads();
    int rank=0, is=0, ni=0;
    if (i<t1){
        float m = nm[i];
        for (int j=0;j<t1;j++){ float a=nm[j]; if (a>m || (a==m && j<i)) rank++; }
        is = (rank<r) ? 1:0;
        ni = NIDX[b*128+i];
    }
    issrc[i]=is; __syncthreads();
    if (i<t1){
        if (is){ SRC[b*16+rank]=i; DST[b*16+rank]=ni; STEP[b*LMAX+2*i] = t1-r+ni; }
        else {
            int cnt=0;
            for (int j=0;j<i;j++) cnt += 1-issrc[j];
            STEP[b*LMAX+2*i]=cnt;
            INV[b*LMAX+cnt]=2*i;
        }
    }
    if (i<t2){ STEP[b*LMAX+2*i+1]=t1-r+i; INV[b*LMAX+(t1-r)+i]=2*i+1; }
}

// ---------------- fused merge ----------------
__global__ __launch_bounds__(256) void merge_fused(const float* __restrict__ X,
        const float* __restrict__ SZ, const int* __restrict__ INV,
        const int* __restrict__ SRC, const int* __restrict__ DST,
        float* __restrict__ XO, float* __restrict__ SZO, int t1, int r)
{
    int p = blockIdx.x, b = blockIdx.y, t = threadIdx.x;
    int base = t1 - r;
    float acc0, acc1, acc2, snew;
    if (p < base){
        int tok = INV[b*LMAX+p];
        float s = SZ[b*LMAX+tok];
        const float* xr = X + (size_t)(b*LMAX+tok)*SD;
        acc0=xr[t]*s; acc1=xr[t+256]*s; acc2=xr[t+512]*s; snew=s;
    } else {
        int d = p - base;
        int tok = 2*d+1;
        float s = SZ[b*LMAX+tok];
        const float* xr = X + (size_t)(b*LMAX+tok)*SD;
        acc0=xr[t]*s; acc1=xr[t+256]*s; acc2=xr[t+512]*s; snew=s;
        for (int k=0;k<r;k++){
            if (DST[b*16+k]==d){
                int st = 2*SRC[b*16+k];
                float ss = SZ[b*LMAX+st];
                const float* xs = X + (size_t)(b*LMAX+st)*SD;
                acc0+=xs[t]*ss; acc1+=xs[t+256]*ss; acc2+=xs[t+512]*ss; snew+=ss;
            }
        }
    }
    float inv = 1.0f/snew;
    float* o = XO + (size_t)(b*LMAX+p)*SD;
    o[t]=acc0*inv; o[t+256]=acc1*inv; o[t+512]=acc2*inv;
    if (t==0) SZO[b*LMAX+p]=snew;
}

// ---------------- token-map update ----------------
__global__ void map_upd(int* __restrict__ MAP, const int* __restrict__ STEP, int mlen)
{
    int i = blockIdx.x*256+threadIdx.x;
    if (i >= NB*mlen) return;
    int b=i/mlen, t=i-b*mlen;
    MAP[b*LMAX+t] = STEP[b*LMAX + MAP[b*LMAX+t]];
}

// ---------------- patchify (split output) ----------------
__global__ void patchify(const float* __restrict__ X, ushort* __restrict__ PHi,
        ushort* __restrict__ PLo)
{
    size_t i = (size_t)blockIdx.x*256 + threadIdx.x;
    if (i >= (size_t)NB*196*768) return;
    int f = i % 768; size_t q = i/768; int p = q % 196; int b = q/196;
    int c = f >> 8, py = (f>>4)&15, px = f&15;
    int gy = p/14, gx = p - gy*14;
    float v = X[(((size_t)b*3 + c)*224 + gy*16+py)*224 + gx*16+px];
    ushort h,l; split_bf16(v,h,l);
    size_t o = ((size_t)(b*LMAX+p))*768 + f;
    PHi[o]=h; PLo[o]=l;
}

__global__ void assemble(const float* __restrict__ T, const float* __restrict__ cls,
        const float* __restrict__ pos, float* __restrict__ Xo)
{
    size_t i = (size_t)blockIdx.x*256 + threadIdx.x;
    if (i >= (size_t)NB*LMAX*768) return;
    int d = i % 768; size_t q = i/768; int n = q % LMAX; int b = q/LMAX;
    float v = (n==0) ? cls[d] : T[((size_t)(b*LMAX+n-1))*768+d];
    Xo[((size_t)(b*LMAX+n))*768+d] = v + pos[n*768+d];
}

__global__ void init_state(float* __restrict__ SZ, int* __restrict__ TMAP, int* __restrict__ SMAP)
{
    int i = blockIdx.x*256+threadIdx.x;
    if (i >= NB*LMAX) return;
    SZ[i]=1.0f;
    int n=i%LMAX;
    TMAP[i]=n;
    if (n<149) SMAP[i]=n;
}

// ---------------- head ----------------
__global__ void head_k(const float* __restrict__ XG, const int* __restrict__ SMAP,
        const int* __restrict__ TMAP, const float* __restrict__ HW,
        const float* __restrict__ HB, float* __restrict__ OUT)
{
    int t = threadIdx.x;
    if (t>=80) return;
    int b=t/10, o=t-b*10;
    int row = SMAP[b*LMAX + TMAP[b*LMAX]];
    const float* xr = XG + ((size_t)(b*LMAX+row))*SD;
    float acc = HB[o];
    for (int d=0;d<SD;d++) acc += xr[d]*HW[d*10+o];
    OUT[b*10+o]=acc;
}

extern "C" void kernel_launch(void* const* d_in, const int* in_sizes, int n_in,
                              void* d_out, int out_size, void* d_ws, size_t ws_size,
                              hipStream_t stream)
{
    const float* x_in    = (const float*)d_in[0];
    const float* patch_w = (const float*)d_in[1];
    const float* patch_b = (const float*)d_in[2];
    const float* cls     = (const float*)d_in[3];
    const float* pos     = (const float*)d_in[4];
    const float* l_ng    = (const float*)d_in[5];
    const float* l_nb    = (const float*)d_in[6];
    const float* g_ng    = (const float*)d_in[7];
    const float* g_nb    = (const float*)d_in[8];
    const float* head_w  = (const float*)d_in[9];
    const float* head_b  = (const float*)d_in[10];
    const float* L[12];  for (int i=0;i<12;i++) L[i]  = (const float*)d_in[11+i];
    const float* Gp[12]; for (int i=0;i<12;i++) Gp[i] = (const float*)d_in[23+i];
    float* out = (float*)d_out;

    float* fp = (float*)d_ws;
    float* xA      = fp; fp += (size_t)NB*LMAX*SD;
    float* xB      = fp; fp += (size_t)NB*LMAX*SD;
    float* qkvbuf  = fp; fp += (size_t)NB*LMAX*2304;
    float* metricbuf=fp; fp += (size_t)NB*LMAX*64;
    float* partbuf = fp; fp += (size_t)4*NB*LMAX*SD;   // split-K partials
    float* szA     = fp; fp += NB*LMAX;
    float* szB     = fp; fp += NB*LMAX;
    float* nodemax = fp; fp += NB*128;
    int* ip = (int*)fp;
    int* tmap    = ip; ip += NB*LMAX;
    int* smap    = ip; ip += NB*LMAX;
    int* stepbuf = ip; ip += NB*LMAX;
    int* invrow  = ip; ip += NB*LMAX;
    int* nodeidx = ip; ip += NB*128;
    int* srcs    = ip; ip += NB*16;
    int* dsts    = ip; ip += NB*16;
    uintptr_t up = ((uintptr_t)ip + 15) & ~(uintptr_t)15;
    ushort* sp = (ushort*)up;
    ushort* lnHi = sp; sp += (size_t)NB*LMAX*SD;
    ushort* lnLo = sp; sp += (size_t)NB*LMAX*SD;
    ushort* oHi  = sp; sp += (size_t)NB*LMAX*SD;
    ushort* oLo  = sp; sp += (size_t)NB*LMAX*SD;
    ushort* hHi  = sp; sp += (size_t)NB*LMAX*3072;
    ushort* hLo  = sp; sp += (size_t)NB*LMAX*3072;
    ushort* pHi  = sp; sp += (size_t)NB*LMAX*SD;
    ushort* pLo  = sp; sp += (size_t)NB*LMAX*SD;
    ushort* patchHi = sp; sp += (size_t)768*768;
    ushort* patchLo = sp; sp += (size_t)768*768;
    ushort* qkvHi = sp; sp += (size_t)4*768*2304;
    ushort* qkvLo = sp; sp += (size_t)4*768*2304;
    ushort* projHi= sp; sp += (size_t)4*768*768;
    ushort* projLo= sp; sp += (size_t)4*768*768;
    ushort* fc1Hi = sp; sp += (size_t)4*768*3072;
    ushort* fc1Lo = sp; sp += (size_t)4*768*3072;
    ushort* fc2Hi = sp; sp += (size_t)4*3072*768;
    ushort* fc2Lo = sp; sp += (size_t)4*3072*768;

    float *xc = xA, *xn = xB, *szc = szA, *szn = szB;

    auto conv_chunk = [&](const float* qw, const float* pw, const float* f1w,
                          const float* f2w, int nz)
    {
        wconv<<<dim3(2304/32,768/32,nz),256,0,stream>>>(qw, qkvHi, qkvLo, SD, 2304);
        wconv<<<dim3(768/32,768/32,nz),256,0,stream>>>(pw, projHi, projLo, SD, SD);
        wconv<<<dim3(3072/32,768/32,nz),256,0,stream>>>(f1w, fc1Hi, fc1Lo, SD, 3072);
        wconv<<<dim3(768/32,3072/32,nz),256,0,stream>>>(f2w, fc2Hi, fc2Lo, 3072, SD);
    };

    auto run_block = [&](const float* ln1g, const float* ln1b, const float* qb,
                         const float* pb, const float* ln2g, const float* ln2b,
                         const float* f1b, const float* f2b,
                         int slot, int N, int r, int* mp, int mlen)
    {
        int M = NB*N;
        int Mt = (M+63)/64;
        const ushort* qH = qkvHi + (size_t)slot*768*2304;
        const ushort* qL = qkvLo + (size_t)slot*768*2304;
        const ushort* pH = projHi + (size_t)slot*768*768;
        const ushort* pL = projLo + (size_t)slot*768*768;
        const ushort* f1H = fc1Hi + (size_t)slot*768*3072;
        const ushort* f1L = fc1Lo + (size_t)slot*768*3072;
        const ushort* f2H = fc2Hi + (size_t)slot*3072*768;
        const ushort* f2L = fc2Lo + (size_t)slot*3072*768;

        ln_split<<<dim3(N,NB),256,0,stream>>>(xc, ln1g, ln1b, lnHi, lnLo);
        gemm_mfma<0,1><<<36*Mt,256,0,stream>>>(lnHi, lnLo, qH, qL, qb, nullptr, qkvbuf, nullptr, nullptr, nullptr, M, 2304, SD, N, 36);
        attn_tile<<<dim3((N+QBLK-1)/QBLK,NHEAD,NB),256,0,stream>>>(qkvbuf, szc, oHi, oLo, N);
        metric_k<<<dim3((N+3)/4,NB),256,0,stream>>>(qkvbuf, metricbuf, N);
        // proj: split-K=4 partials + deterministic reduce (bias+residual)
        gemm_mfma<0,4><<<12*Mt*4,256,0,stream>>>(oHi, oLo, pH, pL, nullptr, nullptr, nullptr, nullptr, nullptr, partbuf, M, SD, SD, N, 12);
        reduce_k<<<(M*(SD/4)+255)/256,256,0,stream>>>(partbuf, pb, xc, xc, M, SD, 4, N);
        int t1=(N+1)/2, t2=N/2, Nn=N-r;
        scores_k<<<dim3(t1,NB),128,0,stream>>>(metricbuf, nodemax, nodeidx, t2);
        plan_k<<<NB,128,0,stream>>>(nodemax, nodeidx, srcs, dsts, stepbuf, invrow, t1, t2, r);
        merge_fused<<<dim3(Nn,NB),256,0,stream>>>(xc, szc, invrow, srcs, dsts, xn, szn, t1, r);
        map_upd<<<(NB*mlen+255)/256,256,0,stream>>>(mp, stepbuf, mlen);
        int M2 = NB*Nn;
        int M2t = (M2+63)/64;
        ln_split<<<dim3(Nn,NB),256,0,stream>>>(xn, ln2g, ln2b, lnHi, lnLo);
        gemm_mfma<1,1><<<48*M2t,256,0,stream>>>(lnHi, lnLo, f1H, f1L, f1b, nullptr, nullptr, hHi, hLo, nullptr, M2, 3072, SD, Nn, 48);
        // fc2: split-K=4 partials + deterministic reduce (bias+residual)
        gemm_mfma<0,4><<<12*M2t*4,256,0,stream>>>(hHi, hLo, f2H, f2L, nullptr, nullptr, nullptr, nullptr, nullptr, partbuf, M2, SD, 3072, Nn, 12);
        reduce_k<<<(M2*(SD/4)+255)/256,256,0,stream>>>(partbuf, f2b, xn, xn, M2, SD, 4, Nn);
        float* tf; tf=xc; xc=xn; xn=tf; tf=szc; szc=szn; szn=tf;
    };

    // ---- patch embedding + token assembly ----
    {
        int tot = NB*196*768;
        patchify<<<(tot+255)/256,256,0,stream>>>(x_in, pHi, pLo);
        wconv<<<dim3(768/32,768/32,1),256,0,stream>>>(patch_w, patchHi, patchLo, SD, SD);
        gemm_mfma<0,1><<<12*((NB*196+63)/64),256,0,stream>>>(pHi, pLo, patchHi, patchLo, patch_b, nullptr, qkvbuf, nullptr, nullptr, nullptr, NB*196, SD, SD, 196, 12);
        int tot2 = NB*LMAX*768;
        assemble<<<(tot2+255)/256,256,0,stream>>>(qkvbuf, cls, pos, xc);
        init_state<<<(NB*LMAX+255)/256,256,0,stream>>>(szc, tmap, smap);
    }

    // ---- local encoder: 4 blocks, r=12 ----
    conv_chunk(L[2], L[4], L[8], L[10], 4);
    int N = 197;
    for (int i=0;i<4;i++){
        run_block(L[0]+i*768, L[1]+i*768, L[3]+(size_t)i*2304,
                  L[5]+(size_t)i*768, L[6]+i*768, L[7]+i*768,
                  L[9]+(size_t)i*3072, L[11]+(size_t)i*768,
                  i, N, 12, tmap, 197);
        N -= 12;
    }
    ln_kernel<<<dim3(N,NB),256,0,stream>>>(xc, l_ng, l_nb, xc);

    // ---- global encoder: 12 blocks, r=8, weight chunks of 4 ----
    for (int c=0;c<3;c++){
        conv_chunk(Gp[2]+(size_t)(4*c)*768*2304, Gp[4]+(size_t)(4*c)*768*768,
                   Gp[8]+(size_t)(4*c)*768*3072, Gp[10]+(size_t)(4*c)*3072*768, 4);
        for (int j=0;j<4;j++){
            int i = 4*c+j;
            run_block(Gp[0]+i*768, Gp[1]+i*768, Gp[3]+(size_t)i*2304,
                      Gp[5]+(size_t)i*768, Gp[6]+i*768, Gp[7]+i*768,
                      Gp[9]+(size_t)i*3072, Gp[11]+(size_t)i*768,
                      j, N, 8, smap, 149);
            N -= 8;
        }
    }
    ln_kernel<<<dim3(N,NB),256,0,stream>>>(xc, g_ng, g_nb, qkvbuf);
    head_k<<<1,128,0,stream>>>(qkvbuf, smap, tmap, head_w, head_b, out);
}

// Round 14
// 2710.268 us; speedup vs baseline: 1.1980x; 1.0110x over previous
//
#include <hip/hip_runtime.h>
#include <math.h>

#define NB 8
#define SD 768
#define NHEAD 12
#define LMAX 197
#define QBLK 32
#define KBLK 64

typedef __attribute__((ext_vector_type(8))) short bf16x8;
typedef __attribute__((ext_vector_type(4))) float f32x4;
typedef const __attribute__((address_space(1))) unsigned int gu32_t;
typedef __attribute__((address_space(3))) unsigned int lu32_t;

static __device__ __forceinline__ float geluf(float x){
    return 0.5f*x*(1.0f+erff(x*0.70710678118654752440f));
}

static __device__ __forceinline__ void split_bf16(float v, ushort& h, ushort& l){
    uint u = __float_as_uint(v);
    uint hb = (u + 0x7FFFu + ((u>>16)&1u)) >> 16;
    h = (ushort)hb;
    float rem = v - __uint_as_float(hb<<16);
    uint u2 = __float_as_uint(rem);
    l = (ushort)((u2 + 0x7FFFu + ((u2>>16)&1u)) >> 16);
}

// ---- weight convert+transpose (batched): W[z][K][Nc] fp32 -> Hi/Lo[z][Nc][K]
__global__ __launch_bounds__(256) void wconv(const float* __restrict__ W,
        ushort* __restrict__ Hi, ushort* __restrict__ Lo, int K, int Nc)
{
    __shared__ float tile[32][33];
    int z = blockIdx.z;
    const float* Wz = W + (size_t)z*K*Nc;
    ushort* Hz = Hi + (size_t)z*Nc*K;
    ushort* Lz = Lo + (size_t)z*Nc*K;
    int n0 = blockIdx.x*32, k0 = blockIdx.y*32;
    int tx = threadIdx.x&31, ty = threadIdx.x>>5;
    #pragma unroll
    for (int i=0;i<32;i+=8) tile[ty+i][tx] = Wz[(size_t)(k0+ty+i)*Nc + n0+tx];
    __syncthreads();
    #pragma unroll
    for (int i=0;i<32;i+=8){
        float v = tile[tx][ty+i];
        ushort h,l; split_bf16(v,h,l);
        size_t o = (size_t)(n0+ty+i)*K + k0+tx;
        Hz[o]=h; Lz[o]=l;
    }
}

// ---- split-bf16 MFMA GEMM: BK=32, double-buffered 32KB LDS via
// global_load_lds, counted vmcnt(4). 1D grid with bijective XCD swizzle.
// Bank-conflict fix (both-sides swizzle): LDS[row][p] holds global 16B chunk
// p ^ ((row>>1)&3). No setprio (m190/round-12: hurts lockstep GEMM).
template<int EPI, int SPLITK>
__global__ __launch_bounds__(256) void gemm_mfma(const ushort* __restrict__ AHi,
        const ushort* __restrict__ ALo, const ushort* __restrict__ WHi,
        const ushort* __restrict__ WLo, const float* __restrict__ bias,
        const float* __restrict__ R, float* __restrict__ C,
        ushort* __restrict__ CHi, ushort* __restrict__ CLo,
        float* __restrict__ Part, int M, int Nc, int K, int ntok, int gx)
{
    __shared__ __align__(16) ushort sAhi[2][2048], sAlo[2][2048];
    __shared__ __align__(16) ushort sBhi[2][2048], sBlo[2][2048];
    const int t = threadIdx.x;
    const int nwg = gridDim.x;
    const int qc = nwg>>3, rc = nwg&7;
    const int xcd = blockIdx.x & 7, jj = blockIdx.x >> 3;
    const int wid = (xcd<rc ? xcd*(qc+1) : rc*(qc+1)+(xcd-rc)*qc) + jj;
    const int bx = wid % gx;
    const int t2 = wid / gx;
    const int gy = nwg/(gx*SPLITK);
    const int by = t2 % gy;
    const int bz = t2 / gy;

    const int w = t>>6, l = t&63, lr = l&15, lg = l>>4;
    const int wr = w>>1, wc = w&1;

    const int Ks = K/SPLITK;
    const int kbeg = bz*Ks;
    const int nt = Ks/32;

    const int srow = t>>2;
    const uint schunk = (uint)((((t&3) ^ ((t>>3)&3)))*16);
    int ar = by*64 + srow; if (ar >= M) ar = M-1;
    int ab_ = ar/ntok; int an_ = ar - ab_*ntok;
    size_t aoff = ((size_t)(ab_*LMAX+an_)*K + kbeg)*2 + schunk;
    size_t woff = ((size_t)(bx*64+srow)*K + kbeg)*2 + schunk;
    const char* pAh = (const char*)AHi + aoff;
    const char* pAl = (const char*)ALo + aoff;
    const char* pWh = (const char*)WHi + woff;
    const char* pWl = (const char*)WLo + woff;

    f32x4 acc[2][2];
    #pragma unroll
    for (int i=0;i<2;i++)
        #pragma unroll
        for (int j=0;j<2;j++) acc[i][j] = (f32x4){0.f,0.f,0.f,0.f};

    const uint wb = (uint)(w*512);

    auto stage = [&](int bf, int kt){
        size_t ko = (size_t)kt*64;
        __builtin_amdgcn_global_load_lds((gu32_t*)(pAh+ko), (lu32_t*)&sAhi[bf][wb], 16, 0, 0);
        __builtin_amdgcn_global_load_lds((gu32_t*)(pAl+ko), (lu32_t*)&sAlo[bf][wb], 16, 0, 0);
        __builtin_amdgcn_global_load_lds((gu32_t*)(pWh+ko), (lu32_t*)&sBhi[bf][wb], 16, 0, 0);
        __builtin_amdgcn_global_load_lds((gu32_t*)(pWl+ko), (lu32_t*)&sBlo[bf][wb], 16, 0, 0);
    };

    int buf = 0;
    stage(0, 0);
    for (int kt=0; kt<nt; ++kt){
        if (kt+1 < nt){
            stage(buf^1, kt+1);
            asm volatile("s_waitcnt vmcnt(4)" ::: "memory");
        } else {
            asm volatile("s_waitcnt vmcnt(0)" ::: "memory");
        }
        __builtin_amdgcn_s_barrier();
        bf16x8 ah[2], al[2], bh[2], bl[2];
        #pragma unroll
        for (int m=0;m<2;m++){
            int row = wr*32 + m*16 + lr;
            uint off = (uint)(row*64 + ((lg ^ ((row>>1)&3))<<4));
            ah[m] = *(const bf16x8*)((const char*)&sAhi[buf][0] + off);
            al[m] = *(const bf16x8*)((const char*)&sAlo[buf][0] + off);
        }
        #pragma unroll
        for (int n=0;n<2;n++){
            int col = wc*32 + n*16 + lr;
            uint off = (uint)(col*64 + ((lg ^ ((col>>1)&3))<<4));
            bh[n] = *(const bf16x8*)((const char*)&sBhi[buf][0] + off);
            bl[n] = *(const bf16x8*)((const char*)&sBlo[buf][0] + off);
        }
        #pragma unroll
        for (int m=0;m<2;m++)
            #pragma unroll
            for (int n=0;n<2;n++){
                acc[m][n] = __builtin_amdgcn_mfma_f32_16x16x32_bf16(ah[m], bh[n], acc[m][n], 0,0,0);
                acc[m][n] = __builtin_amdgcn_mfma_f32_16x16x32_bf16(ah[m], bl[n], acc[m][n], 0,0,0);
                acc[m][n] = __builtin_amdgcn_mfma_f32_16x16x32_bf16(al[m], bh[n], acc[m][n], 0,0,0);
            }
        __builtin_amdgcn_s_barrier();
        buf ^= 1;
    }

    if (SPLITK > 1){
        float* Pz = Part + (size_t)bz*M*Nc;
        #pragma unroll
        for (int m=0;m<2;m++){
            #pragma unroll
            for (int n=0;n<2;n++){
                int gcol = bx*64 + wc*32 + n*16 + lr;
                #pragma unroll
                for (int r=0;r<4;r++){
                    int grow = by*64 + wr*32 + m*16 + lg*4 + r;
                    if (grow >= M) continue;
                    Pz[(size_t)grow*Nc + gcol] = acc[m][n][r];
                }
            }
        }
    } else {
        #pragma unroll
        for (int m=0;m<2;m++){
            #pragma unroll
            for (int n=0;n<2;n++){
                int gcol = bx*64 + wc*32 + n*16 + lr;
                float bv = bias[gcol];
                #pragma unroll
                for (int r=0;r<4;r++){
                    int grow = by*64 + wr*32 + m*16 + lg*4 + r;
                    if (grow >= M) continue;
                    int b = grow/ntok; int ni = grow - b*ntok;
                    size_t off = (size_t)(b*LMAX+ni)*Nc + gcol;
                    float v = acc[m][n][r] + bv;
                    if (EPI==1){
                        v = geluf(v);
                        ushort h,lo; split_bf16(v,h,lo);
                        CHi[off]=h; CLo[off]=lo;
                    } else {
                        if (EPI==2) v += R[off];
                        C[off] = v;
                    }
                }
            }
        }
    }
}

// ---- split-K reduce + bias + residual (deterministic fixed order) ----
__global__ __launch_bounds__(256) void reduce_k(const float* __restrict__ P,
        const float* __restrict__ bias, const float* __restrict__ R,
        float* __restrict__ C, int M, int Nc, int S, int ntok)
{
    int idx = blockIdx.x*256 + threadIdx.x;
    int tot = M*(Nc/4);
    if (idx >= tot) return;
    int grow = idx/(Nc/4), c4 = idx - grow*(Nc/4);
    size_t po = (size_t)grow*Nc + c4*4;
    float4 a = *(const float4*)(P + po);
    for (int s=1;s<S;s++){
        float4 v = *(const float4*)(P + (size_t)s*M*Nc + po);
        a.x+=v.x; a.y+=v.y; a.z+=v.z; a.w+=v.w;
    }
    int b = grow/ntok, n = grow - b*ntok;
    size_t off = (size_t)(b*LMAX+n)*Nc + c4*4;
    float4 bv = *(const float4*)(bias + c4*4);
    float4 rv = *(const float4*)(R + off);
    float4 o;
    o.x=a.x+bv.x+rv.x; o.y=a.y+bv.y+rv.y; o.z=a.z+bv.z+rv.z; o.w=a.w+bv.w+rv.w;
    *(float4*)(C + off) = o;
}

// ---------------- block-wide sum over 256 threads ----------------
__device__ __forceinline__ float block_sum256(float v){
    __shared__ float red[4];
    for (int o=32;o>0;o>>=1) v += __shfl_down(v,o,64);
    int t=threadIdx.x;
    if ((t&63)==0) red[t>>6]=v;
    __syncthreads();
    float r = red[0]+red[1]+red[2]+red[3];
    __syncthreads();
    return r;
}

// ---------------- LayerNorm -> split bf16 ----------------
__global__ __launch_bounds__(256) void ln_split(const float* __restrict__ X,
        const float* __restrict__ gam, const float* __restrict__ bet,
        ushort* __restrict__ YHi, ushort* __restrict__ YLo)
{
    int n = blockIdx.x, b = blockIdx.y, t = threadIdx.x;
    const float* xr = X + ((size_t)(b*LMAX+n))*SD;
    size_t ro = ((size_t)(b*LMAX+n))*SD;
    float v0=xr[t], v1=xr[t+256], v2=xr[t+512];
    float mu = block_sum256(v0+v1+v2) * (1.0f/768.0f);
    float d0=v0-mu, d1=v1-mu, d2=v2-mu;
    float var = block_sum256(d0*d0+d1*d1+d2*d2) * (1.0f/768.0f);
    float rs = rsqrtf(var + 1e-6f);
    float y0 = d0*rs*gam[t]     + bet[t];
    float y1 = d1*rs*gam[t+256] + bet[t+256];
    float y2 = d2*rs*gam[t+512] + bet[t+512];
    ushort h,lo;
    split_bf16(y0,h,lo); YHi[ro+t]=h;     YLo[ro+t]=lo;
    split_bf16(y1,h,lo); YHi[ro+t+256]=h; YLo[ro+t+256]=lo;
    split_bf16(y2,h,lo); YHi[ro+t+512]=h; YLo[ro+t+512]=lo;
}

// ---------------- plain LayerNorm (fp32 out) ----------------
__global__ __launch_bounds__(256) void ln_kernel(const float* __restrict__ X,
        const float* __restrict__ gam, const float* __restrict__ bet,
        float* __restrict__ Y)
{
    int n = blockIdx.x, b = blockIdx.y, t = threadIdx.x;
    const float* xr = X + ((size_t)(b*LMAX+n))*SD;
    float* yr = Y + ((size_t)(b*LMAX+n))*SD;
    float v0=xr[t], v1=xr[t+256], v2=xr[t+512];
    float mu = block_sum256(v0+v1+v2) * (1.0f/768.0f);
    float d0=v0-mu, d1=v1-mu, d2=v2-mu;
    float var = block_sum256(d0*d0+d1*d1+d2*d2) * (1.0f/768.0f);
    float rs = rsqrtf(var + 1e-6f);
    yr[t]     = d0*rs*gam[t]     + bet[t];
    yr[t+256] = d1*rs*gam[t+256] + bet[t+256];
    yr[t+512] = d2*rs*gam[t+512] + bet[t+512];
}

// ---------------- tiled attention: one block per (b,h,32-q tile) ----------
__global__ __launch_bounds__(256) void attn_tile(const float* __restrict__ QKV,
        const float* __restrict__ SZ, ushort* __restrict__ OHi,
        ushort* __restrict__ OLo, int N)
{
    const int q0 = blockIdx.x*QBLK;
    const int h = blockIdx.y, b = blockIdx.z, t = threadIdx.x;
    __shared__ float Qs[QBLK][68];
    __shared__ float KVs[KBLK][68];
    __shared__ float Ls[QBLK][200];
    __shared__ float szl[KBLK];
    __shared__ float invs[QBLK];

    {
        int row = t>>3, seg = t&7;
        int q = q0 + row;
        if (q < N){
            const float* src = QKV + ((size_t)(b*LMAX+q))*2304 + h*64 + seg*8;
            *(float4*)&Qs[row][seg*8]   = *(const float4*)src;
            *(float4*)&Qs[row][seg*8+4] = *(const float4*)(src+4);
        } else {
            float4 z = make_float4(0.f,0.f,0.f,0.f);
            *(float4*)&Qs[row][seg*8]   = z;
            *(float4*)&Qs[row][seg*8+4] = z;
        }
    }
    const int tq = t>>3, tk = t&7;
    const int nkt = (N+KBLK-1)/KBLK;

    for (int kt=0; kt<nkt; ++kt){
        int kbase = kt*KBLK;
        __syncthreads();
        {
            int row = t>>2, seg = t&3;
            int ktok = kbase + row;
            float4 a,b4,c,d4;
            if (ktok < N){
                const float* src = QKV + ((size_t)(b*LMAX+ktok))*2304 + 768 + h*64 + seg*16;
                a=*(const float4*)src; b4=*(const float4*)(src+4);
                c=*(const float4*)(src+8); d4=*(const float4*)(src+12);
            } else {
                a=b4=c=d4=make_float4(0.f,0.f,0.f,0.f);
            }
            *(float4*)&KVs[row][seg*16]   =a;
            *(float4*)&KVs[row][seg*16+4] =b4;
            *(float4*)&KVs[row][seg*16+8] =c;
            *(float4*)&KVs[row][seg*16+12]=d4;
            if (t < KBLK){
                int kk2 = kbase + t;
                szl[t] = (kk2<N) ? logf(SZ[b*LMAX+kk2]) : 0.f;
            }
        }
        __syncthreads();
        float acc[8];
        #pragma unroll
        for (int j=0;j<8;j++) acc[j]=0.f;
        #pragma unroll 4
        for (int d4=0; d4<16; ++d4){
            float4 qv = *(const float4*)&Qs[tq][d4*4];
            #pragma unroll
            for (int j=0;j<8;j++){
                float4 kv = *(const float4*)&KVs[tk+8*j][d4*4];
                acc[j] += qv.x*kv.x + qv.y*kv.y + qv.z*kv.z + qv.w*kv.w;
            }
        }
        #pragma unroll
        for (int j=0;j<8;j++){
            int kk = kbase + tk + 8*j;
            if (kk < N) Ls[tq][kk] = acc[j]*0.125f + szl[tk+8*j];
        }
    }
    __syncthreads();

    {
        float m = -INFINITY;
        for (int k=tk;k<N;k+=8) m = fmaxf(m, Ls[tq][k]);
        #pragma unroll
        for (int o=1;o<8;o<<=1) m = fmaxf(m, __shfl_xor(m,o,64));
        float s = 0.f;
        for (int k=tk;k<N;k+=8){
            float p = expf(Ls[tq][k]-m);
            Ls[tq][k]=p; s+=p;
        }
        #pragma unroll
        for (int o=1;o<8;o<<=1) s += __shfl_xor(s,o,64);
        if (tk==0) invs[tq] = 1.0f/s;
    }

    float o0[8];
    #pragma unroll
    for (int i=0;i<8;i++) o0[i]=0.f;
    for (int kt=0; kt<nkt; ++kt){
        int kbase = kt*KBLK;
        __syncthreads();
        {
            int row = t>>2, seg = t&3;
            int ktok = kbase + row;
            float4 a,b4,c,d4;
            if (ktok < N){
                const float* src = QKV + ((size_t)(b*LMAX+ktok))*2304 + 1536 + h*64 + seg*16;
                a=*(const float4*)src; b4=*(const float4*)(src+4);
                c=*(const float4*)(src+8); d4=*(const float4*)(src+12);
            } else {
                a=b4=c=d4=make_float4(0.f,0.f,0.f,0.f);
            }
            *(float4*)&KVs[row][seg*16]   =a;
            *(float4*)&KVs[row][seg*16+4] =b4;
            *(float4*)&KVs[row][seg*16+8] =c;
            *(float4*)&KVs[row][seg*16+12]=d4;
        }
        __syncthreads();
        int kmax = N - kbase; if (kmax > KBLK) kmax = KBLK;
        for (int kk=0; kk<kmax; ++kk){
            float p = Ls[tq][kbase+kk];
            float4 v0 = *(const float4*)&KVs[kk][tk*8];
            float4 v1 = *(const float4*)&KVs[kk][tk*8+4];
            o0[0]+=p*v0.x; o0[1]+=p*v0.y; o0[2]+=p*v0.z; o0[3]+=p*v0.w;
            o0[4]+=p*v1.x; o0[5]+=p*v1.y; o0[6]+=p*v1.z; o0[7]+=p*v1.w;
        }
    }
    int q = q0 + tq;
    if (q < N){
        float inv = invs[tq];
        ushort hh[8], ll[8];
        #pragma unroll
        for (int i=0;i<8;i++){ split_bf16(o0[i]*inv, hh[i], ll[i]); }
        size_t o = ((size_t)(b*LMAX+q))*SD + h*64 + tk*8;
        *(ushort4*)(OHi+o)   = make_ushort4(hh[0],hh[1],hh[2],hh[3]);
        *(ushort4*)(OHi+o+4) = make_ushort4(hh[4],hh[5],hh[6],hh[7]);
        *(ushort4*)(OLo+o)   = make_ushort4(ll[0],ll[1],ll[2],ll[3]);
        *(ushort4*)(OLo+o+4) = make_ushort4(ll[4],ll[5],ll[6],ll[7]);
    }
}

// ---------------- metric = mean_h(k), L2-normalized; 4 tokens/block --------
__global__ __launch_bounds__(256) void metric_k(const float* __restrict__ QKV,
        float* __restrict__ MET, int N)
{
    const int b = blockIdx.y;
    const int sub = threadIdx.x>>6, d = threadIdx.x&63;
    const int n = blockIdx.x*4 + sub;
    if (n >= N) return;
    const float* base = QKV + ((size_t)(b*LMAX+n))*2304 + 768 + d;
    float s=0.f;
    #pragma unroll
    for (int h=0;h<12;h++) s += base[h*64];
    s *= (1.0f/12.0f);
    float sq = s*s;
    for (int o=32;o>0;o>>=1) sq += __shfl_down(sq,o,64);
    float nrm = sqrtf(__shfl(sq,0,64));
    MET[((size_t)(b*LMAX+n))*64 + d] = s/nrm;
}

// ---------------- scores + per-row (max, argmax) ----------------
__global__ __launch_bounds__(128) void scores_k(const float* __restrict__ MET,
        float* __restrict__ NMAX, int* __restrict__ NIDX, int t2)
{
    const int i = blockIdx.x, b = blockIdx.y, t = threadIdx.x;
    __shared__ float ma[64];
    __shared__ float vals[128];
    __shared__ int idxs[128];
    if (t<64) ma[t] = MET[((size_t)(b*LMAX+2*i))*64+t];
    __syncthreads();
    float val = -INFINITY;
    if (t<t2 && i>0){
        const float* mb = MET + ((size_t)(b*LMAX+2*t+1))*64;
        float dot=0.f;
        #pragma unroll 8
        for (int dd=0;dd<64;dd++) dot += ma[dd]*mb[dd];
        val = dot;
    }
    vals[t]=val; idxs[t]=t; __syncthreads();
    for (int s=64;s>0;s>>=1){
        if (t<s){
            float v2=vals[t+s], v1=vals[t]; int i2=idxs[t+s];
            if (v2>v1 || (v2==v1 && i2<idxs[t])){ vals[t]=v2; idxs[t]=i2; }
        }
        __syncthreads();
    }
    if (t==0){ NMAX[b*128+i]=vals[0]; NIDX[b*128+i]=idxs[0]; }
}

// ---------------- plan ----------------
__global__ __launch_bounds__(128) void plan_k(const float* __restrict__ NMAX,
        const int* __restrict__ NIDX, int* __restrict__ SRC, int* __restrict__ DST,
        int* __restrict__ STEP, int* __restrict__ INV, int t1, int t2, int r)
{
    const int b = blockIdx.x, i = threadIdx.x;
    __shared__ float nm[128];
    __shared__ int issrc[128];
    nm[i] = (i<t1) ? NMAX[b*128+i] : INFINITY;
    __syncthreads();
    int rank=0, is=0, ni=0;
    if (i<t1){
        float m = nm[i];
        for (int j=0;j<t1;j++){ float a=nm[j]; if (a>m || (a==m && j<i)) rank++; }
        is = (rank<r) ? 1:0;
        ni = NIDX[b*128+i];
    }
    issrc[i]=is; __syncthreads();
    if (i<t1){
        if (is){ SRC[b*16+rank]=i; DST[b*16+rank]=ni; STEP[b*LMAX+2*i] = t1-r+ni; }
        else {
            int cnt=0;
            for (int j=0;j<i;j++) cnt += 1-issrc[j];
            STEP[b*LMAX+2*i]=cnt;
            INV[b*LMAX+cnt]=2*i;
        }
    }
    if (i<t2){ STEP[b*LMAX+2*i+1]=t1-r+i; INV[b*LMAX+(t1-r)+i]=2*i+1; }
}

// ---- fused merge + LN2 + bf16-split (single-variable experiment vs r13):
// merged row is in registers -> layernorm it here, write x, size, and the
// split-bf16 LN output directly; deletes the second ln_split pass.
__global__ __launch_bounds__(256) void merge_ln(const float* __restrict__ X,
        const float* __restrict__ SZ, const int* __restrict__ INV,
        const int* __restrict__ SRC, const int* __restrict__ DST,
        const float* __restrict__ gam, const float* __restrict__ bet,
        float* __restrict__ XO, float* __restrict__ SZO,
        ushort* __restrict__ YHi, ushort* __restrict__ YLo, int t1, int r)
{
    int p = blockIdx.x, b = blockIdx.y, t = threadIdx.x;
    int base = t1 - r;
    float acc0, acc1, acc2, snew;
    if (p < base){
        int tok = INV[b*LMAX+p];
        float s = SZ[b*LMAX+tok];
        const float* xr = X + (size_t)(b*LMAX+tok)*SD;
        acc0=xr[t]*s; acc1=xr[t+256]*s; acc2=xr[t+512]*s; snew=s;
    } else {
        int d = p - base;
        int tok = 2*d+1;
        float s = SZ[b*LMAX+tok];
        const float* xr = X + (size_t)(b*LMAX+tok)*SD;
        acc0=xr[t]*s; acc1=xr[t+256]*s; acc2=xr[t+512]*s; snew=s;
        for (int k=0;k<r;k++){
            if (DST[b*16+k]==d){
                int st = 2*SRC[b*16+k];
                float ss = SZ[b*LMAX+st];
                const float* xs = X + (size_t)(b*LMAX+st)*SD;
                acc0+=xs[t]*ss; acc1+=xs[t+256]*ss; acc2+=xs[t+512]*ss; snew+=ss;
            }
        }
    }
    float inv = 1.0f/snew;
    float x0=acc0*inv, x1=acc1*inv, x2=acc2*inv;
    size_t ro = (size_t)(b*LMAX+p)*SD;
    float* o = XO + ro;
    o[t]=x0; o[t+256]=x1; o[t+512]=x2;
    if (t==0) SZO[b*LMAX+p]=snew;
    float mu = block_sum256(x0+x1+x2) * (1.0f/768.0f);
    float d0=x0-mu, d1=x1-mu, d2=x2-mu;
    float var = block_sum256(d0*d0+d1*d1+d2*d2) * (1.0f/768.0f);
    float rs = rsqrtf(var + 1e-6f);
    float y0 = d0*rs*gam[t]     + bet[t];
    float y1 = d1*rs*gam[t+256] + bet[t+256];
    float y2 = d2*rs*gam[t+512] + bet[t+512];
    ushort h,lo;
    split_bf16(y0,h,lo); YHi[ro+t]=h;     YLo[ro+t]=lo;
    split_bf16(y1,h,lo); YHi[ro+t+256]=h; YLo[ro+t+256]=lo;
    split_bf16(y2,h,lo); YHi[ro+t+512]=h; YLo[ro+t+512]=lo;
}

// ---------------- token-map update ----------------
__global__ void map_upd(int* __restrict__ MAP, const int* __restrict__ STEP, int mlen)
{
    int i = blockIdx.x*256+threadIdx.x;
    if (i >= NB*mlen) return;
    int b=i/mlen, t=i-b*mlen;
    MAP[b*LMAX+t] = STEP[b*LMAX + MAP[b*LMAX+t]];
}

// ---------------- patchify (split output) ----------------
__global__ void patchify(const float* __restrict__ X, ushort* __restrict__ PHi,
        ushort* __restrict__ PLo)
{
    size_t i = (size_t)blockIdx.x*256 + threadIdx.x;
    if (i >= (size_t)NB*196*768) return;
    int f = i % 768; size_t q = i/768; int p = q % 196; int b = q/196;
    int c = f >> 8, py = (f>>4)&15, px = f&15;
    int gy = p/14, gx = p - gy*14;
    float v = X[(((size_t)b*3 + c)*224 + gy*16+py)*224 + gx*16+px];
    ushort h,l; split_bf16(v,h,l);
    size_t o = ((size_t)(b*LMAX+p))*768 + f;
    PHi[o]=h; PLo[o]=l;
}

__global__ void assemble(const float* __restrict__ T, const float* __restrict__ cls,
        const float* __restrict__ pos, float* __restrict__ Xo)
{
    size_t i = (size_t)blockIdx.x*256 + threadIdx.x;
    if (i >= (size_t)NB*LMAX*768) return;
    int d = i % 768; size_t q = i/768; int n = q % LMAX; int b = q/LMAX;
    float v = (n==0) ? cls[d] : T[((size_t)(b*LMAX+n-1))*768+d];
    Xo[((size_t)(b*LMAX+n))*768+d] = v + pos[n*768+d];
}

__global__ void init_state(float* __restrict__ SZ, int* __restrict__ TMAP, int* __restrict__ SMAP)
{
    int i = blockIdx.x*256+threadIdx.x;
    if (i >= NB*LMAX) return;
    SZ[i]=1.0f;
    int n=i%LMAX;
    TMAP[i]=n;
    if (n<149) SMAP[i]=n;
}

// ---------------- head ----------------
__global__ void head_k(const float* __restrict__ XG, const int* __restrict__ SMAP,
        const int* __restrict__ TMAP, const float* __restrict__ HW,
        const float* __restrict__ HB, float* __restrict__ OUT)
{
    int t = threadIdx.x;
    if (t>=80) return;
    int b=t/10, o=t-b*10;
    int row = SMAP[b*LMAX + TMAP[b*LMAX]];
    const float* xr = XG + ((size_t)(b*LMAX+row))*SD;
    float acc = HB[o];
    for (int d=0;d<SD;d++) acc += xr[d]*HW[d*10+o];
    OUT[b*10+o]=acc;
}

extern "C" void kernel_launch(void* const* d_in, const int* in_sizes, int n_in,
                              void* d_out, int out_size, void* d_ws, size_t ws_size,
                              hipStream_t stream)
{
    const float* x_in    = (const float*)d_in[0];
    const float* patch_w = (const float*)d_in[1];
    const float* patch_b = (const float*)d_in[2];
    const float* cls     = (const float*)d_in[3];
    const float* pos     = (const float*)d_in[4];
    const float* l_ng    = (const float*)d_in[5];
    const float* l_nb    = (const float*)d_in[6];
    const float* g_ng    = (const float*)d_in[7];
    const float* g_nb    = (const float*)d_in[8];
    const float* head_w  = (const float*)d_in[9];
    const float* head_b  = (const float*)d_in[10];
    const float* L[12];  for (int i=0;i<12;i++) L[i]  = (const float*)d_in[11+i];
    const float* Gp[12]; for (int i=0;i<12;i++) Gp[i] = (const float*)d_in[23+i];
    float* out = (float*)d_out;

    float* fp = (float*)d_ws;
    float* xA      = fp; fp += (size_t)NB*LMAX*SD;
    float* xB      = fp; fp += (size_t)NB*LMAX*SD;
    float* qkvbuf  = fp; fp += (size_t)NB*LMAX*2304;
    float* metricbuf=fp; fp += (size_t)NB*LMAX*64;
    float* partbuf = fp; fp += (size_t)4*NB*LMAX*SD;   // split-K partials
    float* szA     = fp; fp += NB*LMAX;
    float* szB     = fp; fp += NB*LMAX;
    float* nodemax = fp; fp += NB*128;
    int* ip = (int*)fp;
    int* tmap    = ip; ip += NB*LMAX;
    int* smap    = ip; ip += NB*LMAX;
    int* stepbuf = ip; ip += NB*LMAX;
    int* invrow  = ip; ip += NB*LMAX;
    int* nodeidx = ip; ip += NB*128;
    int* srcs    = ip; ip += NB*16;
    int* dsts    = ip; ip += NB*16;
    uintptr_t up = ((uintptr_t)ip + 15) & ~(uintptr_t)15;
    ushort* sp = (ushort*)up;
    ushort* lnHi = sp; sp += (size_t)NB*LMAX*SD;
    ushort* lnLo = sp; sp += (size_t)NB*LMAX*SD;
    ushort* oHi  = sp; sp += (size_t)NB*LMAX*SD;
    ushort* oLo  = sp; sp += (size_t)NB*LMAX*SD;
    ushort* hHi  = sp; sp += (size_t)NB*LMAX*3072;
    ushort* hLo  = sp; sp += (size_t)NB*LMAX*3072;
    ushort* pHi  = sp; sp += (size_t)NB*LMAX*SD;
    ushort* pLo  = sp; sp += (size_t)NB*LMAX*SD;
    ushort* patchHi = sp; sp += (size_t)768*768;
    ushort* patchLo = sp; sp += (size_t)768*768;
    ushort* qkvHi = sp; sp += (size_t)4*768*2304;
    ushort* qkvLo = sp; sp += (size_t)4*768*2304;
    ushort* projHi= sp; sp += (size_t)4*768*768;
    ushort* projLo= sp; sp += (size_t)4*768*768;
    ushort* fc1Hi = sp; sp += (size_t)4*768*3072;
    ushort* fc1Lo = sp; sp += (size_t)4*768*3072;
    ushort* fc2Hi = sp; sp += (size_t)4*3072*768;
    ushort* fc2Lo = sp; sp += (size_t)4*3072*768;

    float *xc = xA, *xn = xB, *szc = szA, *szn = szB;

    auto conv_chunk = [&](const float* qw, const float* pw, const float* f1w,
                          const float* f2w, int nz)
    {
        wconv<<<dim3(2304/32,768/32,nz),256,0,stream>>>(qw, qkvHi, qkvLo, SD, 2304);
        wconv<<<dim3(768/32,768/32,nz),256,0,stream>>>(pw, projHi, projLo, SD, SD);
        wconv<<<dim3(3072/32,768/32,nz),256,0,stream>>>(f1w, fc1Hi, fc1Lo, SD, 3072);
        wconv<<<dim3(768/32,3072/32,nz),256,0,stream>>>(f2w, fc2Hi, fc2Lo, 3072, SD);
    };

    auto run_block = [&](const float* ln1g, const float* ln1b, const float* qb,
                         const float* pb, const float* ln2g, const float* ln2b,
                         const float* f1b, const float* f2b,
                         int slot, int N, int r, int* mp, int mlen)
    {
        int M = NB*N;
        int Mt = (M+63)/64;
        const ushort* qH = qkvHi + (size_t)slot*768*2304;
        const ushort* qL = qkvLo + (size_t)slot*768*2304;
        const ushort* pH = projHi + (size_t)slot*768*768;
        const ushort* pL = projLo + (size_t)slot*768*768;
        const ushort* f1H = fc1Hi + (size_t)slot*768*3072;
        const ushort* f1L = fc1Lo + (size_t)slot*768*3072;
        const ushort* f2H = fc2Hi + (size_t)slot*3072*768;
        const ushort* f2L = fc2Lo + (size_t)slot*3072*768;

        ln_split<<<dim3(N,NB),256,0,stream>>>(xc, ln1g, ln1b, lnHi, lnLo);
        gemm_mfma<0,1><<<36*Mt,256,0,stream>>>(lnHi, lnLo, qH, qL, qb, nullptr, qkvbuf, nullptr, nullptr, nullptr, M, 2304, SD, N, 36);
        attn_tile<<<dim3((N+QBLK-1)/QBLK,NHEAD,NB),256,0,stream>>>(qkvbuf, szc, oHi, oLo, N);
        metric_k<<<dim3((N+3)/4,NB),256,0,stream>>>(qkvbuf, metricbuf, N);
        // proj: split-K=4 partials + deterministic reduce (bias+residual)
        gemm_mfma<0,4><<<12*Mt*4,256,0,stream>>>(oHi, oLo, pH, pL, nullptr, nullptr, nullptr, nullptr, nullptr, partbuf, M, SD, SD, N, 12);
        reduce_k<<<(M*(SD/4)+255)/256,256,0,stream>>>(partbuf, pb, xc, xc, M, SD, 4, N);
        int t1=(N+1)/2, t2=N/2, Nn=N-r;
        scores_k<<<dim3(t1,NB),128,0,stream>>>(metricbuf, nodemax, nodeidx, t2);
        plan_k<<<NB,128,0,stream>>>(nodemax, nodeidx, srcs, dsts, stepbuf, invrow, t1, t2, r);
        // fused merge + LN2 + split (replaces merge_fused + second ln_split)
        merge_ln<<<dim3(Nn,NB),256,0,stream>>>(xc, szc, invrow, srcs, dsts, ln2g, ln2b, xn, szn, lnHi, lnLo, t1, r);
        map_upd<<<(NB*mlen+255)/256,256,0,stream>>>(mp, stepbuf, mlen);
        int M2 = NB*Nn;
        int M2t = (M2+63)/64;
        gemm_mfma<1,1><<<48*M2t,256,0,stream>>>(lnHi, lnLo, f1H, f1L, f1b, nullptr, nullptr, hHi, hLo, nullptr, M2, 3072, SD, Nn, 48);
        // fc2: split-K=4 partials + deterministic reduce (bias+residual)
        gemm_mfma<0,4><<<12*M2t*4,256,0,stream>>>(hHi, hLo, f2H, f2L, nullptr, nullptr, nullptr, nullptr, nullptr, partbuf, M2, SD, 3072, Nn, 12);
        reduce_k<<<(M2*(SD/4)+255)/256,256,0,stream>>>(partbuf, f2b, xn, xn, M2, SD, 4, Nn);
        float* tf; tf=xc; xc=xn; xn=tf; tf=szc; szc=szn; szn=tf;
    };

    // ---- patch embedding + token assembly ----
    {
        int tot = NB*196*768;
        patchify<<<(tot+255)/256,256,0,stream>>>(x_in, pHi, pLo);
        wconv<<<dim3(768/32,768/32,1),256,0,stream>>>(patch_w, patchHi, patchLo, SD, SD);
        gemm_mfma<0,1><<<12*((NB*196+63)/64),256,0,stream>>>(pHi, pLo, patchHi, patchLo, patch_b, nullptr, qkvbuf, nullptr, nullptr, nullptr, NB*196, SD, SD, 196, 12);
        int tot2 = NB*LMAX*768;
        assemble<<<(tot2+255)/256,256,0,stream>>>(qkvbuf, cls, pos, xc);
        init_state<<<(NB*LMAX+255)/256,256,0,stream>>>(szc, tmap, smap);
    }

    // ---- local encoder: 4 blocks, r=12 ----
    conv_chunk(L[2], L[4], L[8], L[10], 4);
    int N = 197;
    for (int i=0;i<4;i++){
        run_block(L[0]+i*768, L[1]+i*768, L[3]+(size_t)i*2304,
                  L[5]+(size_t)i*768, L[6]+i*768, L[7]+i*768,
                  L[9]+(size_t)i*3072, L[11]+(size_t)i*768,
                  i, N, 12, tmap, 197);
        N -= 12;
    }
    ln_kernel<<<dim3(N,NB),256,0,stream>>>(xc, l_ng, l_nb, xc);

    // ---- global encoder: 12 blocks, r=8, weight chunks of 4 ----
    for (int c=0;c<3;c++){
        conv_chunk(Gp[2]+(size_t)(4*c)*768*2304, Gp[4]+(size_t)(4*c)*768*768,
                   Gp[8]+(size_t)(4*c)*768*3072, Gp[10]+(size_t)(4*c)*3072*768, 4);
        for (int j=0;j<4;j++){
            int i = 4*c+j;
            run_block(Gp[0]+i*768, Gp[1]+i*768, Gp[3]+(size_t)i*2304,
                      Gp[5]+(size_t)i*768, Gp[6]+i*768, Gp[7]+i*768,
                      Gp[9]+(size_t)i*3072, Gp[11]+(size_t)i*768,
                      j, N, 8, smap, 149);
            N -= 8;
        }
    }
    ln_kernel<<<dim3(N,NB),256,0,stream>>>(xc, g_ng, g_nb, qkvbuf);
    head_k<<<1,128,0,stream>>>(qkvbuf, smap, tmap, head_w, head_b, out);
}

// Round 15
// 2664.689 us; speedup vs baseline: 1.2185x; 1.0171x over previous
//
#include <hip/hip_runtime.h>
#include <math.h>

#define NB 8
#define SD 768
#define NHEAD 12
#define LMAX 197
#define QBLK 32
#define KBLK 64

typedef __attribute__((ext_vector_type(8))) short bf16x8;
typedef __attribute__((ext_vector_type(4))) float f32x4;
typedef const __attribute__((address_space(1))) unsigned int gu32_t;
typedef __attribute__((address_space(3))) unsigned int lu32_t;

static __device__ __forceinline__ float geluf(float x){
    return 0.5f*x*(1.0f+erff(x*0.70710678118654752440f));
}

static __device__ __forceinline__ void split_bf16(float v, ushort& h, ushort& l){
    uint u = __float_as_uint(v);
    uint hb = (u + 0x7FFFu + ((u>>16)&1u)) >> 16;
    h = (ushort)hb;
    float rem = v - __uint_as_float(hb<<16);
    uint u2 = __float_as_uint(rem);
    l = (ushort)((u2 + 0x7FFFu + ((u2>>16)&1u)) >> 16);
}

// ---- weight convert+transpose (batched): W[z][K][Nc] fp32 -> Hi/Lo[z][Nc][K]
__global__ __launch_bounds__(256) void wconv(const float* __restrict__ W,
        ushort* __restrict__ Hi, ushort* __restrict__ Lo, int K, int Nc)
{
    __shared__ float tile[32][33];
    int z = blockIdx.z;
    const float* Wz = W + (size_t)z*K*Nc;
    ushort* Hz = Hi + (size_t)z*Nc*K;
    ushort* Lz = Lo + (size_t)z*Nc*K;
    int n0 = blockIdx.x*32, k0 = blockIdx.y*32;
    int tx = threadIdx.x&31, ty = threadIdx.x>>5;
    #pragma unroll
    for (int i=0;i<32;i+=8) tile[ty+i][tx] = Wz[(size_t)(k0+ty+i)*Nc + n0+tx];
    __syncthreads();
    #pragma unroll
    for (int i=0;i<32;i+=8){
        float v = tile[tx][ty+i];
        ushort h,l; split_bf16(v,h,l);
        size_t o = (size_t)(n0+ty+i)*K + k0+tx;
        Hz[o]=h; Lz[o]=l;
    }
}

// ---- split-bf16 MFMA GEMM: BK=32, double-buffered 32KB LDS via
// global_load_lds, counted vmcnt(4). 1D grid with bijective XCD swizzle.
// Bank-conflict fix (both-sides swizzle): LDS[row][p] holds global 16B chunk
// p ^ ((row>>1)&3). No setprio (m190/round-12: hurts lockstep GEMM).
template<int EPI, int SPLITK>
__global__ __launch_bounds__(256) void gemm_mfma(const ushort* __restrict__ AHi,
        const ushort* __restrict__ ALo, const ushort* __restrict__ WHi,
        const ushort* __restrict__ WLo, const float* __restrict__ bias,
        const float* __restrict__ R, float* __restrict__ C,
        ushort* __restrict__ CHi, ushort* __restrict__ CLo,
        float* __restrict__ Part, int M, int Nc, int K, int ntok, int gx)
{
    __shared__ __align__(16) ushort sAhi[2][2048], sAlo[2][2048];
    __shared__ __align__(16) ushort sBhi[2][2048], sBlo[2][2048];
    const int t = threadIdx.x;
    const int nwg = gridDim.x;
    const int qc = nwg>>3, rc = nwg&7;
    const int xcd = blockIdx.x & 7, jj = blockIdx.x >> 3;
    const int wid = (xcd<rc ? xcd*(qc+1) : rc*(qc+1)+(xcd-rc)*qc) + jj;
    const int bx = wid % gx;
    const int t2 = wid / gx;
    const int gy = nwg/(gx*SPLITK);
    const int by = t2 % gy;
    const int bz = t2 / gy;

    const int w = t>>6, l = t&63, lr = l&15, lg = l>>4;
    const int wr = w>>1, wc = w&1;

    const int Ks = K/SPLITK;
    const int kbeg = bz*Ks;
    const int nt = Ks/32;

    const int srow = t>>2;
    const uint schunk = (uint)((((t&3) ^ ((t>>3)&3)))*16);
    int ar = by*64 + srow; if (ar >= M) ar = M-1;
    int ab_ = ar/ntok; int an_ = ar - ab_*ntok;
    size_t aoff = ((size_t)(ab_*LMAX+an_)*K + kbeg)*2 + schunk;
    size_t woff = ((size_t)(bx*64+srow)*K + kbeg)*2 + schunk;
    const char* pAh = (const char*)AHi + aoff;
    const char* pAl = (const char*)ALo + aoff;
    const char* pWh = (const char*)WHi + woff;
    const char* pWl = (const char*)WLo + woff;

    f32x4 acc[2][2];
    #pragma unroll
    for (int i=0;i<2;i++)
        #pragma unroll
        for (int j=0;j<2;j++) acc[i][j] = (f32x4){0.f,0.f,0.f,0.f};

    const uint wb = (uint)(w*512);

    auto stage = [&](int bf, int kt){
        size_t ko = (size_t)kt*64;
        __builtin_amdgcn_global_load_lds((gu32_t*)(pAh+ko), (lu32_t*)&sAhi[bf][wb], 16, 0, 0);
        __builtin_amdgcn_global_load_lds((gu32_t*)(pAl+ko), (lu32_t*)&sAlo[bf][wb], 16, 0, 0);
        __builtin_amdgcn_global_load_lds((gu32_t*)(pWh+ko), (lu32_t*)&sBhi[bf][wb], 16, 0, 0);
        __builtin_amdgcn_global_load_lds((gu32_t*)(pWl+ko), (lu32_t*)&sBlo[bf][wb], 16, 0, 0);
    };

    int buf = 0;
    stage(0, 0);
    for (int kt=0; kt<nt; ++kt){
        if (kt+1 < nt){
            stage(buf^1, kt+1);
            asm volatile("s_waitcnt vmcnt(4)" ::: "memory");
        } else {
            asm volatile("s_waitcnt vmcnt(0)" ::: "memory");
        }
        __builtin_amdgcn_s_barrier();
        bf16x8 ah[2], al[2], bh[2], bl[2];
        #pragma unroll
        for (int m=0;m<2;m++){
            int row = wr*32 + m*16 + lr;
            uint off = (uint)(row*64 + ((lg ^ ((row>>1)&3))<<4));
            ah[m] = *(const bf16x8*)((const char*)&sAhi[buf][0] + off);
            al[m] = *(const bf16x8*)((const char*)&sAlo[buf][0] + off);
        }
        #pragma unroll
        for (int n=0;n<2;n++){
            int col = wc*32 + n*16 + lr;
            uint off = (uint)(col*64 + ((lg ^ ((col>>1)&3))<<4));
            bh[n] = *(const bf16x8*)((const char*)&sBhi[buf][0] + off);
            bl[n] = *(const bf16x8*)((const char*)&sBlo[buf][0] + off);
        }
        #pragma unroll
        for (int m=0;m<2;m++)
            #pragma unroll
            for (int n=0;n<2;n++){
                acc[m][n] = __builtin_amdgcn_mfma_f32_16x16x32_bf16(ah[m], bh[n], acc[m][n], 0,0,0);
                acc[m][n] = __builtin_amdgcn_mfma_f32_16x16x32_bf16(ah[m], bl[n], acc[m][n], 0,0,0);
                acc[m][n] = __builtin_amdgcn_mfma_f32_16x16x32_bf16(al[m], bh[n], acc[m][n], 0,0,0);
            }
        __builtin_amdgcn_s_barrier();
        buf ^= 1;
    }

    if (SPLITK > 1){
        float* Pz = Part + (size_t)bz*M*Nc;
        #pragma unroll
        for (int m=0;m<2;m++){
            #pragma unroll
            for (int n=0;n<2;n++){
                int gcol = bx*64 + wc*32 + n*16 + lr;
                #pragma unroll
                for (int r=0;r<4;r++){
                    int grow = by*64 + wr*32 + m*16 + lg*4 + r;
                    if (grow >= M) continue;
                    Pz[(size_t)grow*Nc + gcol] = acc[m][n][r];
                }
            }
        }
    } else {
        #pragma unroll
        for (int m=0;m<2;m++){
            #pragma unroll
            for (int n=0;n<2;n++){
                int gcol = bx*64 + wc*32 + n*16 + lr;
                float bv = bias[gcol];
                #pragma unroll
                for (int r=0;r<4;r++){
                    int grow = by*64 + wr*32 + m*16 + lg*4 + r;
                    if (grow >= M) continue;
                    int b = grow/ntok; int ni = grow - b*ntok;
                    size_t off = (size_t)(b*LMAX+ni)*Nc + gcol;
                    float v = acc[m][n][r] + bv;
                    if (EPI==1){
                        v = geluf(v);
                        ushort h,lo; split_bf16(v,h,lo);
                        CHi[off]=h; CLo[off]=lo;
                    } else {
                        if (EPI==2) v += R[off];
                        C[off] = v;
                    }
                }
            }
        }
    }
}

// ---- split-K reduce + bias + residual (element grid, deterministic) ----
__global__ __launch_bounds__(256) void reduce_k(const float* __restrict__ P,
        const float* __restrict__ bias, const float* __restrict__ R,
        float* __restrict__ C, int M, int Nc, int S, int ntok)
{
    int idx = blockIdx.x*256 + threadIdx.x;
    int tot = M*(Nc/4);
    if (idx >= tot) return;
    int grow = idx/(Nc/4), c4 = idx - grow*(Nc/4);
    size_t po = (size_t)grow*Nc + c4*4;
    float4 a = *(const float4*)(P + po);
    for (int s=1;s<S;s++){
        float4 v = *(const float4*)(P + (size_t)s*M*Nc + po);
        a.x+=v.x; a.y+=v.y; a.z+=v.z; a.w+=v.w;
    }
    int b = grow/ntok, n = grow - b*ntok;
    size_t off = (size_t)(b*LMAX+n)*Nc + c4*4;
    float4 bv = *(const float4*)(bias + c4*4);
    float4 rv = *(const float4*)(R + off);
    float4 o;
    o.x=a.x+bv.x+rv.x; o.y=a.y+bv.y+rv.y; o.z=a.z+bv.z+rv.z; o.w=a.w+bv.w+rv.w;
    *(float4*)(C + off) = o;
}

// ---------------- block-wide sum over 256 threads ----------------
__device__ __forceinline__ float block_sum256(float v){
    __shared__ float red[4];
    for (int o=32;o>0;o>>=1) v += __shfl_down(v,o,64);
    int t=threadIdx.x;
    if ((t&63)==0) red[t>>6]=v;
    __syncthreads();
    float r = red[0]+red[1]+red[2]+red[3];
    __syncthreads();
    return r;
}

// ---- fc2 split-K reduce (one block per row, 256 thr x 3 cols) + bias +
// residual + fused NEXT-block LN1 + bf16-split. Same slab order s=0..3,
// same block_sum LN pattern as ln_split -> bit-identical math.
__global__ __launch_bounds__(256) void reduce_ln(const float* __restrict__ P,
        const float* __restrict__ bias, const float* __restrict__ R,
        float* __restrict__ C, const float* __restrict__ gam,
        const float* __restrict__ bet, ushort* __restrict__ YHi,
        ushort* __restrict__ YLo, int M, int ntok)
{
    int row = blockIdx.x, t = threadIdx.x;
    int b = row/ntok, n = row - b*ntok;
    size_t off = (size_t)(b*LMAX+n)*SD;
    size_t po = (size_t)row*SD;
    float x0,x1,x2;
    {
        float a0=P[po+t], a1=P[po+t+256], a2=P[po+t+512];
        #pragma unroll
        for (int s=1;s<4;s++){
            size_t ps = (size_t)s*M*SD + po;
            a0 += P[ps+t]; a1 += P[ps+t+256]; a2 += P[ps+t+512];
        }
        x0 = a0 + bias[t]     + R[off+t];
        x1 = a1 + bias[t+256] + R[off+t+256];
        x2 = a2 + bias[t+512] + R[off+t+512];
        C[off+t]=x0; C[off+t+256]=x1; C[off+t+512]=x2;
    }
    float mu = block_sum256(x0+x1+x2) * (1.0f/768.0f);
    float d0=x0-mu, d1=x1-mu, d2=x2-mu;
    float var = block_sum256(d0*d0+d1*d1+d2*d2) * (1.0f/768.0f);
    float rs = rsqrtf(var + 1e-6f);
    float y0 = d0*rs*gam[t]     + bet[t];
    float y1 = d1*rs*gam[t+256] + bet[t+256];
    float y2 = d2*rs*gam[t+512] + bet[t+512];
    ushort h,lo;
    split_bf16(y0,h,lo); YHi[off+t]=h;     YLo[off+t]=lo;
    split_bf16(y1,h,lo); YHi[off+t+256]=h; YLo[off+t+256]=lo;
    split_bf16(y2,h,lo); YHi[off+t+512]=h; YLo[off+t+512]=lo;
}

// ---------------- LayerNorm -> split bf16 ----------------
__global__ __launch_bounds__(256) void ln_split(const float* __restrict__ X,
        const float* __restrict__ gam, const float* __restrict__ bet,
        ushort* __restrict__ YHi, ushort* __restrict__ YLo)
{
    int n = blockIdx.x, b = blockIdx.y, t = threadIdx.x;
    const float* xr = X + ((size_t)(b*LMAX+n))*SD;
    size_t ro = ((size_t)(b*LMAX+n))*SD;
    float v0=xr[t], v1=xr[t+256], v2=xr[t+512];
    float mu = block_sum256(v0+v1+v2) * (1.0f/768.0f);
    float d0=v0-mu, d1=v1-mu, d2=v2-mu;
    float var = block_sum256(d0*d0+d1*d1+d2*d2) * (1.0f/768.0f);
    float rs = rsqrtf(var + 1e-6f);
    float y0 = d0*rs*gam[t]     + bet[t];
    float y1 = d1*rs*gam[t+256] + bet[t+256];
    float y2 = d2*rs*gam[t+512] + bet[t+512];
    ushort h,lo;
    split_bf16(y0,h,lo); YHi[ro+t]=h;     YLo[ro+t]=lo;
    split_bf16(y1,h,lo); YHi[ro+t+256]=h; YLo[ro+t+256]=lo;
    split_bf16(y2,h,lo); YHi[ro+t+512]=h; YLo[ro+t+512]=lo;
}

// ---------------- plain LayerNorm (fp32 out) ----------------
__global__ __launch_bounds__(256) void ln_kernel(const float* __restrict__ X,
        const float* __restrict__ gam, const float* __restrict__ bet,
        float* __restrict__ Y)
{
    int n = blockIdx.x, b = blockIdx.y, t = threadIdx.x;
    const float* xr = X + ((size_t)(b*LMAX+n))*SD;
    float* yr = Y + ((size_t)(b*LMAX+n))*SD;
    float v0=xr[t], v1=xr[t+256], v2=xr[t+512];
    float mu = block_sum256(v0+v1+v2) * (1.0f/768.0f);
    float d0=v0-mu, d1=v1-mu, d2=v2-mu;
    float var = block_sum256(d0*d0+d1*d1+d2*d2) * (1.0f/768.0f);
    float rs = rsqrtf(var + 1e-6f);
    yr[t]     = d0*rs*gam[t]     + bet[t];
    yr[t+256] = d1*rs*gam[t+256] + bet[t+256];
    yr[t+512] = d2*rs*gam[t+512] + bet[t+512];
}

// ---------------- tiled attention: one block per (b,h,32-q tile) ----------
__global__ __launch_bounds__(256) void attn_tile(const float* __restrict__ QKV,
        const float* __restrict__ SZ, ushort* __restrict__ OHi,
        ushort* __restrict__ OLo, int N)
{
    const int q0 = blockIdx.x*QBLK;
    const int h = blockIdx.y, b = blockIdx.z, t = threadIdx.x;
    __shared__ float Qs[QBLK][68];
    __shared__ float KVs[KBLK][68];
    __shared__ float Ls[QBLK][200];
    __shared__ float szl[KBLK];
    __shared__ float invs[QBLK];

    {
        int row = t>>3, seg = t&7;
        int q = q0 + row;
        if (q < N){
            const float* src = QKV + ((size_t)(b*LMAX+q))*2304 + h*64 + seg*8;
            *(float4*)&Qs[row][seg*8]   = *(const float4*)src;
            *(float4*)&Qs[row][seg*8+4] = *(const float4*)(src+4);
        } else {
            float4 z = make_float4(0.f,0.f,0.f,0.f);
            *(float4*)&Qs[row][seg*8]   = z;
            *(float4*)&Qs[row][seg*8+4] = z;
        }
    }
    const int tq = t>>3, tk = t&7;
    const int nkt = (N+KBLK-1)/KBLK;

    for (int kt=0; kt<nkt; ++kt){
        int kbase = kt*KBLK;
        __syncthreads();
        {
            int row = t>>2, seg = t&3;
            int ktok = kbase + row;
            float4 a,b4,c,d4;
            if (ktok < N){
                const float* src = QKV + ((size_t)(b*LMAX+ktok))*2304 + 768 + h*64 + seg*16;
                a=*(const float4*)src; b4=*(const float4*)(src+4);
                c=*(const float4*)(src+8); d4=*(const float4*)(src+12);
            } else {
                a=b4=c=d4=make_float4(0.f,0.f,0.f,0.f);
            }
            *(float4*)&KVs[row][seg*16]   =a;
            *(float4*)&KVs[row][seg*16+4] =b4;
            *(float4*)&KVs[row][seg*16+8] =c;
            *(float4*)&KVs[row][seg*16+12]=d4;
            if (t < KBLK){
                int kk2 = kbase + t;
                szl[t] = (kk2<N) ? logf(SZ[b*LMAX+kk2]) : 0.f;
            }
        }
        __syncthreads();
        float acc[8];
        #pragma unroll
        for (int j=0;j<8;j++) acc[j]=0.f;
        #pragma unroll 4
        for (int d4=0; d4<16; ++d4){
            float4 qv = *(const float4*)&Qs[tq][d4*4];
            #pragma unroll
            for (int j=0;j<8;j++){
                float4 kv = *(const float4*)&KVs[tk+8*j][d4*4];
                acc[j] += qv.x*kv.x + qv.y*kv.y + qv.z*kv.z + qv.w*kv.w;
            }
        }
        #pragma unroll
        for (int j=0;j<8;j++){
            int kk = kbase + tk + 8*j;
            if (kk < N) Ls[tq][kk] = acc[j]*0.125f + szl[tk+8*j];
        }
    }
    __syncthreads();

    {
        float m = -INFINITY;
        for (int k=tk;k<N;k+=8) m = fmaxf(m, Ls[tq][k]);
        #pragma unroll
        for (int o=1;o<8;o<<=1) m = fmaxf(m, __shfl_xor(m,o,64));
        float s = 0.f;
        for (int k=tk;k<N;k+=8){
            float p = expf(Ls[tq][k]-m);
            Ls[tq][k]=p; s+=p;
        }
        #pragma unroll
        for (int o=1;o<8;o<<=1) s += __shfl_xor(s,o,64);
        if (tk==0) invs[tq] = 1.0f/s;
    }

    float o0[8];
    #pragma unroll
    for (int i=0;i<8;i++) o0[i]=0.f;
    for (int kt=0; kt<nkt; ++kt){
        int kbase = kt*KBLK;
        __syncthreads();
        {
            int row = t>>2, seg = t&3;
            int ktok = kbase + row;
            float4 a,b4,c,d4;
            if (ktok < N){
                const float* src = QKV + ((size_t)(b*LMAX+ktok))*2304 + 1536 + h*64 + seg*16;
                a=*(const float4*)src; b4=*(const float4*)(src+4);
                c=*(const float4*)(src+8); d4=*(const float4*)(src+12);
            } else {
                a=b4=c=d4=make_float4(0.f,0.f,0.f,0.f);
            }
            *(float4*)&KVs[row][seg*16]   =a;
            *(float4*)&KVs[row][seg*16+4] =b4;
            *(float4*)&KVs[row][seg*16+8] =c;
            *(float4*)&KVs[row][seg*16+12]=d4;
        }
        __syncthreads();
        int kmax = N - kbase; if (kmax > KBLK) kmax = KBLK;
        for (int kk=0; kk<kmax; ++kk){
            float p = Ls[tq][kbase+kk];
            float4 v0 = *(const float4*)&KVs[kk][tk*8];
            float4 v1 = *(const float4*)&KVs[kk][tk*8+4];
            o0[0]+=p*v0.x; o0[1]+=p*v0.y; o0[2]+=p*v0.z; o0[3]+=p*v0.w;
            o0[4]+=p*v1.x; o0[5]+=p*v1.y; o0[6]+=p*v1.z; o0[7]+=p*v1.w;
        }
    }
    int q = q0 + tq;
    if (q < N){
        float inv = invs[tq];
        ushort hh[8], ll[8];
        #pragma unroll
        for (int i=0;i<8;i++){ split_bf16(o0[i]*inv, hh[i], ll[i]); }
        size_t o = ((size_t)(b*LMAX+q))*SD + h*64 + tk*8;
        *(ushort4*)(OHi+o)   = make_ushort4(hh[0],hh[1],hh[2],hh[3]);
        *(ushort4*)(OHi+o+4) = make_ushort4(hh[4],hh[5],hh[6],hh[7]);
        *(ushort4*)(OLo+o)   = make_ushort4(ll[0],ll[1],ll[2],ll[3]);
        *(ushort4*)(OLo+o+4) = make_ushort4(ll[4],ll[5],ll[6],ll[7]);
    }
}

// ---------------- metric = mean_h(k), L2-normalized; 4 tokens/block --------
__global__ __launch_bounds__(256) void metric_k(const float* __restrict__ QKV,
        float* __restrict__ MET, int N)
{
    const int b = blockIdx.y;
    const int sub = threadIdx.x>>6, d = threadIdx.x&63;
    const int n = blockIdx.x*4 + sub;
    if (n >= N) return;
    const float* base = QKV + ((size_t)(b*LMAX+n))*2304 + 768 + d;
    float s=0.f;
    #pragma unroll
    for (int h=0;h<12;h++) s += base[h*64];
    s *= (1.0f/12.0f);
    float sq = s*s;
    for (int o=32;o>0;o>>=1) sq += __shfl_down(sq,o,64);
    float nrm = sqrtf(__shfl(sq,0,64));
    MET[((size_t)(b*LMAX+n))*64 + d] = s/nrm;
}

// ---------------- scores + per-row (max, argmax) ----------------
__global__ __launch_bounds__(128) void scores_k(const float* __restrict__ MET,
        float* __restrict__ NMAX, int* __restrict__ NIDX, int t2)
{
    const int i = blockIdx.x, b = blockIdx.y, t = threadIdx.x;
    __shared__ float ma[64];
    __shared__ float vals[128];
    __shared__ int idxs[128];
    if (t<64) ma[t] = MET[((size_t)(b*LMAX+2*i))*64+t];
    __syncthreads();
    float val = -INFINITY;
    if (t<t2 && i>0){
        const float* mb = MET + ((size_t)(b*LMAX+2*t+1))*64;
        float dot=0.f;
        #pragma unroll 8
        for (int dd=0;dd<64;dd++) dot += ma[dd]*mb[dd];
        val = dot;
    }
    vals[t]=val; idxs[t]=t; __syncthreads();
    for (int s=64;s>0;s>>=1){
        if (t<s){
            float v2=vals[t+s], v1=vals[t]; int i2=idxs[t+s];
            if (v2>v1 || (v2==v1 && i2<idxs[t])){ vals[t]=v2; idxs[t]=i2; }
        }
        __syncthreads();
    }
    if (t==0){ NMAX[b*128+i]=vals[0]; NIDX[b*128+i]=idxs[0]; }
}

// ---------------- plan ----------------
__global__ __launch_bounds__(128) void plan_k(const float* __restrict__ NMAX,
        const int* __restrict__ NIDX, int* __restrict__ SRC, int* __restrict__ DST,
        int* __restrict__ STEP, int* __restrict__ INV, int t1, int t2, int r)
{
    const int b = blockIdx.x, i = threadIdx.x;
    __shared__ float nm[128];
    __shared__ int issrc[128];
    nm[i] = (i<t1) ? NMAX[b*128+i] : INFINITY;
    __syncthreads();
    int rank=0, is=0, ni=0;
    if (i<t1){
        float m = nm[i];
        for (int j=0;j<t1;j++){ float a=nm[j]; if (a>m || (a==m && j<i)) rank++; }
        is = (rank<r) ? 1:0;
        ni = NIDX[b*128+i];
    }
    issrc[i]=is; __syncthreads();
    if (i<t1){
        if (is){ SRC[b*16+rank]=i; DST[b*16+rank]=ni; STEP[b*LMAX+2*i] = t1-r+ni; }
        else {
            int cnt=0;
            for (int j=0;j<i;j++) cnt += 1-issrc[j];
            STEP[b*LMAX+2*i]=cnt;
            INV[b*LMAX+cnt]=2*i;
        }
    }
    if (i<t2){ STEP[b*LMAX+2*i+1]=t1-r+i; INV[b*LMAX+(t1-r)+i]=2*i+1; }
}

// ---- fused merge + LN2 + bf16-split ----
__global__ __launch_bounds__(256) void merge_ln(const float* __restrict__ X,
        const float* __restrict__ SZ, const int* __restrict__ INV,
        const int* __restrict__ SRC, const int* __restrict__ DST,
        const float* __restrict__ gam, const float* __restrict__ bet,
        float* __restrict__ XO, float* __restrict__ SZO,
        ushort* __restrict__ YHi, ushort* __restrict__ YLo, int t1, int r)
{
    int p = blockIdx.x, b = blockIdx.y, t = threadIdx.x;
    int base = t1 - r;
    float acc0, acc1, acc2, snew;
    if (p < base){
        int tok = INV[b*LMAX+p];
        float s = SZ[b*LMAX+tok];
        const float* xr = X + (size_t)(b*LMAX+tok)*SD;
        acc0=xr[t]*s; acc1=xr[t+256]*s; acc2=xr[t+512]*s; snew=s;
    } else {
        int d = p - base;
        int tok = 2*d+1;
        float s = SZ[b*LMAX+tok];
        const float* xr = X + (size_t)(b*LMAX+tok)*SD;
        acc0=xr[t]*s; acc1=xr[t+256]*s; acc2=xr[t+512]*s; snew=s;
        for (int k=0;k<r;k++){
            if (DST[b*16+k]==d){
                int st = 2*SRC[b*16+k];
                float ss = SZ[b*LMAX+st];
                const float* xs = X + (size_t)(b*LMAX+st)*SD;
                acc0+=xs[t]*ss; acc1+=xs[t+256]*ss; acc2+=xs[t+512]*ss; snew+=ss;
            }
        }
    }
    float inv = 1.0f/snew;
    float x0=acc0*inv, x1=acc1*inv, x2=acc2*inv;
    size_t ro = (size_t)(b*LMAX+p)*SD;
    float* o = XO + ro;
    o[t]=x0; o[t+256]=x1; o[t+512]=x2;
    if (t==0) SZO[b*LMAX+p]=snew;
    float mu = block_sum256(x0+x1+x2) * (1.0f/768.0f);
    float d0=x0-mu, d1=x1-mu, d2=x2-mu;
    float var = block_sum256(d0*d0+d1*d1+d2*d2) * (1.0f/768.0f);
    float rs = rsqrtf(var + 1e-6f);
    float y0 = d0*rs*gam[t]     + bet[t];
    float y1 = d1*rs*gam[t+256] + bet[t+256];
    float y2 = d2*rs*gam[t+512] + bet[t+512];
    ushort h,lo;
    split_bf16(y0,h,lo); YHi[ro+t]=h;     YLo[ro+t]=lo;
    split_bf16(y1,h,lo); YHi[ro+t+256]=h; YLo[ro+t+256]=lo;
    split_bf16(y2,h,lo); YHi[ro+t+512]=h; YLo[ro+t+512]=lo;
}

// ---------------- token-map update ----------------
__global__ void map_upd(int* __restrict__ MAP, const int* __restrict__ STEP, int mlen)
{
    int i = blockIdx.x*256+threadIdx.x;
    if (i >= NB*mlen) return;
    int b=i/mlen, t=i-b*mlen;
    MAP[b*LMAX+t] = STEP[b*LMAX + MAP[b*LMAX+t]];
}

// ---------------- patchify (split output) ----------------
__global__ void patchify(const float* __restrict__ X, ushort* __restrict__ PHi,
        ushort* __restrict__ PLo)
{
    size_t i = (size_t)blockIdx.x*256 + threadIdx.x;
    if (i >= (size_t)NB*196*768) return;
    int f = i % 768; size_t q = i/768; int p = q % 196; int b = q/196;
    int c = f >> 8, py = (f>>4)&15, px = f&15;
    int gy = p/14, gx = p - gy*14;
    float v = X[(((size_t)b*3 + c)*224 + gy*16+py)*224 + gx*16+px];
    ushort h,l; split_bf16(v,h,l);
    size_t o = ((size_t)(b*LMAX+p))*768 + f;
    PHi[o]=h; PLo[o]=l;
}

__global__ void assemble(const float* __restrict__ T, const float* __restrict__ cls,
        const float* __restrict__ pos, float* __restrict__ Xo)
{
    size_t i = (size_t)blockIdx.x*256 + threadIdx.x;
    if (i >= (size_t)NB*LMAX*768) return;
    int d = i % 768; size_t q = i/768; int n = q % LMAX; int b = q/LMAX;
    float v = (n==0) ? cls[d] : T[((size_t)(b*LMAX+n-1))*768+d];
    Xo[((size_t)(b*LMAX+n))*768+d] = v + pos[n*768+d];
}

__global__ void init_state(float* __restrict__ SZ, int* __restrict__ TMAP, int* __restrict__ SMAP)
{
    int i = blockIdx.x*256+threadIdx.x;
    if (i >= NB*LMAX) return;
    SZ[i]=1.0f;
    int n=i%LMAX;
    TMAP[i]=n;
    if (n<149) SMAP[i]=n;
}

// ---------------- head ----------------
__global__ void head_k(const float* __restrict__ XG, const int* __restrict__ SMAP,
        const int* __restrict__ TMAP, const float* __restrict__ HW,
        const float* __restrict__ HB, float* __restrict__ OUT)
{
    int t = threadIdx.x;
    if (t>=80) return;
    int b=t/10, o=t-b*10;
    int row = SMAP[b*LMAX + TMAP[b*LMAX]];
    const float* xr = XG + ((size_t)(b*LMAX+row))*SD;
    float acc = HB[o];
    for (int d=0;d<SD;d++) acc += xr[d]*HW[d*10+o];
    OUT[b*10+o]=acc;
}

extern "C" void kernel_launch(void* const* d_in, const int* in_sizes, int n_in,
                              void* d_out, int out_size, void* d_ws, size_t ws_size,
                              hipStream_t stream)
{
    const float* x_in    = (const float*)d_in[0];
    const float* patch_w = (const float*)d_in[1];
    const float* patch_b = (const float*)d_in[2];
    const float* cls     = (const float*)d_in[3];
    const float* pos     = (const float*)d_in[4];
    const float* l_ng    = (const float*)d_in[5];
    const float* l_nb    = (const float*)d_in[6];
    const float* g_ng    = (const float*)d_in[7];
    const float* g_nb    = (const float*)d_in[8];
    const float* head_w  = (const float*)d_in[9];
    const float* head_b  = (const float*)d_in[10];
    const float* L[12];  for (int i=0;i<12;i++) L[i]  = (const float*)d_in[11+i];
    const float* Gp[12]; for (int i=0;i<12;i++) Gp[i] = (const float*)d_in[23+i];
    float* out = (float*)d_out;

    float* fp = (float*)d_ws;
    float* xA      = fp; fp += (size_t)NB*LMAX*SD;
    float* xB      = fp; fp += (size_t)NB*LMAX*SD;
    float* qkvbuf  = fp; fp += (size_t)NB*LMAX*2304;
    float* metricbuf=fp; fp += (size_t)NB*LMAX*64;
    float* partbuf = fp; fp += (size_t)4*NB*LMAX*SD;   // split-K partials
    float* szA     = fp; fp += NB*LMAX;
    float* szB     = fp; fp += NB*LMAX;
    float* nodemax = fp; fp += NB*128;
    int* ip = (int*)fp;
    int* tmap    = ip; ip += NB*LMAX;
    int* smap    = ip; ip += NB*LMAX;
    int* stepbuf = ip; ip += NB*LMAX;
    int* invrow  = ip; ip += NB*LMAX;
    int* nodeidx = ip; ip += NB*128;
    int* srcs    = ip; ip += NB*16;
    int* dsts    = ip; ip += NB*16;
    uintptr_t up = ((uintptr_t)ip + 15) & ~(uintptr_t)15;
    ushort* sp = (ushort*)up;
    ushort* lnHi = sp; sp += (size_t)NB*LMAX*SD;
    ushort* lnLo = sp; sp += (size_t)NB*LMAX*SD;
    ushort* oHi  = sp; sp += (size_t)NB*LMAX*SD;
    ushort* oLo  = sp; sp += (size_t)NB*LMAX*SD;
    ushort* hHi  = sp; sp += (size_t)NB*LMAX*3072;
    ushort* hLo  = sp; sp += (size_t)NB*LMAX*3072;
    ushort* pHi  = sp; sp += (size_t)NB*LMAX*SD;
    ushort* pLo  = sp; sp += (size_t)NB*LMAX*SD;
    ushort* patchHi = sp; sp += (size_t)768*768;
    ushort* patchLo = sp; sp += (size_t)768*768;
    ushort* qkvHi = sp; sp += (size_t)4*768*2304;
    ushort* qkvLo = sp; sp += (size_t)4*768*2304;
    ushort* projHi= sp; sp += (size_t)4*768*768;
    ushort* projLo= sp; sp += (size_t)4*768*768;
    ushort* fc1Hi = sp; sp += (size_t)4*768*3072;
    ushort* fc1Lo = sp; sp += (size_t)4*768*3072;
    ushort* fc2Hi = sp; sp += (size_t)4*3072*768;
    ushort* fc2Lo = sp; sp += (size_t)4*3072*768;

    float *xc = xA, *xn = xB, *szc = szA, *szn = szB;

    auto conv_chunk = [&](const float* qw, const float* pw, const float* f1w,
                          const float* f2w, int nz)
    {
        wconv<<<dim3(2304/32,768/32,nz),256,0,stream>>>(qw, qkvHi, qkvLo, SD, 2304);
        wconv<<<dim3(768/32,768/32,nz),256,0,stream>>>(pw, projHi, projLo, SD, SD);
        wconv<<<dim3(3072/32,768/32,nz),256,0,stream>>>(f1w, fc1Hi, fc1Lo, SD, 3072);
        wconv<<<dim3(768/32,3072/32,nz),256,0,stream>>>(f2w, fc2Hi, fc2Lo, 3072, SD);
    };

    auto run_block = [&](const float* ln1g, const float* ln1b, const float* qb,
                         const float* pb, const float* ln2g, const float* ln2b,
                         const float* f1b, const float* f2b,
                         int slot, int N, int r, int* mp, int mlen,
                         bool lead, const float* nln_g, const float* nln_b)
    {
        int M = NB*N;
        int Mt = (M+63)/64;
        const ushort* qH = qkvHi + (size_t)slot*768*2304;
        const ushort* qL = qkvLo + (size_t)slot*768*2304;
        const ushort* pH = projHi + (size_t)slot*768*768;
        const ushort* pL = projLo + (size_t)slot*768*768;
        const ushort* f1H = fc1Hi + (size_t)slot*768*3072;
        const ushort* f1L = fc1Lo + (size_t)slot*768*3072;
        const ushort* f2H = fc2Hi + (size_t)slot*3072*768;
        const ushort* f2L = fc2Lo + (size_t)slot*3072*768;

        if (lead)
            ln_split<<<dim3(N,NB),256,0,stream>>>(xc, ln1g, ln1b, lnHi, lnLo);
        gemm_mfma<0,1><<<36*Mt,256,0,stream>>>(lnHi, lnLo, qH, qL, qb, nullptr, qkvbuf, nullptr, nullptr, nullptr, M, 2304, SD, N, 36);
        attn_tile<<<dim3((N+QBLK-1)/QBLK,NHEAD,NB),256,0,stream>>>(qkvbuf, szc, oHi, oLo, N);
        metric_k<<<dim3((N+3)/4,NB),256,0,stream>>>(qkvbuf, metricbuf, N);
        // proj: split-K=4 partials + deterministic reduce (bias+residual)
        gemm_mfma<0,4><<<12*Mt*4,256,0,stream>>>(oHi, oLo, pH, pL, nullptr, nullptr, nullptr, nullptr, nullptr, partbuf, M, SD, SD, N, 12);
        reduce_k<<<(M*(SD/4)+255)/256,256,0,stream>>>(partbuf, pb, xc, xc, M, SD, 4, N);
        int t1=(N+1)/2, t2=N/2, Nn=N-r;
        scores_k<<<dim3(t1,NB),128,0,stream>>>(metricbuf, nodemax, nodeidx, t2);
        plan_k<<<NB,128,0,stream>>>(nodemax, nodeidx, srcs, dsts, stepbuf, invrow, t1, t2, r);
        // fused merge + LN2 + split
        merge_ln<<<dim3(Nn,NB),256,0,stream>>>(xc, szc, invrow, srcs, dsts, ln2g, ln2b, xn, szn, lnHi, lnLo, t1, r);
        map_upd<<<(NB*mlen+255)/256,256,0,stream>>>(mp, stepbuf, mlen);
        int M2 = NB*Nn;
        int M2t = (M2+63)/64;
        gemm_mfma<1,1><<<48*M2t,256,0,stream>>>(lnHi, lnLo, f1H, f1L, f1b, nullptr, nullptr, hHi, hLo, nullptr, M2, 3072, SD, Nn, 48);
        // fc2: split-K=4 partials + reduce (+ fused next-block LN1+split)
        gemm_mfma<0,4><<<12*M2t*4,256,0,stream>>>(hHi, hLo, f2H, f2L, nullptr, nullptr, nullptr, nullptr, nullptr, partbuf, M2, SD, 3072, Nn, 12);
        if (nln_g)
            reduce_ln<<<M2,256,0,stream>>>(partbuf, f2b, xn, xn, nln_g, nln_b, lnHi, lnLo, M2, Nn);
        else
            reduce_k<<<(M2*(SD/4)+255)/256,256,0,stream>>>(partbuf, f2b, xn, xn, M2, SD, 4, Nn);
        float* tf; tf=xc; xc=xn; xn=tf; tf=szc; szc=szn; szn=tf;
    };

    // ---- patch embedding + token assembly ----
    {
        int tot = NB*196*768;
        patchify<<<(tot+255)/256,256,0,stream>>>(x_in, pHi, pLo);
        wconv<<<dim3(768/32,768/32,1),256,0,stream>>>(patch_w, patchHi, patchLo, SD, SD);
        gemm_mfma<0,1><<<12*((NB*196+63)/64),256,0,stream>>>(pHi, pLo, patchHi, patchLo, patch_b, nullptr, qkvbuf, nullptr, nullptr, nullptr, NB*196, SD, SD, 196, 12);
        int tot2 = NB*LMAX*768;
        assemble<<<(tot2+255)/256,256,0,stream>>>(qkvbuf, cls, pos, xc);
        init_state<<<(NB*LMAX+255)/256,256,0,stream>>>(szc, tmap, smap);
    }

    // ---- local encoder: 4 blocks, r=12 ----
    conv_chunk(L[2], L[4], L[8], L[10], 4);
    int N = 197;
    for (int i=0;i<4;i++){
        const float* ng  = (i<3) ? L[0]+(i+1)*768 : nullptr;
        const float* nb2 = (i<3) ? L[1]+(i+1)*768 : nullptr;
        run_block(L[0]+i*768, L[1]+i*768, L[3]+(size_t)i*2304,
                  L[5]+(size_t)i*768, L[6]+i*768, L[7]+i*768,
                  L[9]+(size_t)i*3072, L[11]+(size_t)i*768,
                  i, N, 12, tmap, 197, i==0, ng, nb2);
        N -= 12;
    }
    ln_kernel<<<dim3(N,NB),256,0,stream>>>(xc, l_ng, l_nb, xc);

    // ---- global encoder: 12 blocks, r=8, weight chunks of 4 ----
    for (int c=0;c<3;c++){
        conv_chunk(Gp[2]+(size_t)(4*c)*768*2304, Gp[4]+(size_t)(4*c)*768*768,
                   Gp[8]+(size_t)(4*c)*768*3072, Gp[10]+(size_t)(4*c)*3072*768, 4);
        for (int j=0;j<4;j++){
            int i = 4*c+j;
            const float* ng  = (i<11) ? Gp[0]+(i+1)*768 : nullptr;
            const float* nb2 = (i<11) ? Gp[1]+(i+1)*768 : nullptr;
            run_block(Gp[0]+i*768, Gp[1]+i*768, Gp[3]+(size_t)i*2304,
                      Gp[5]+(size_t)i*768, Gp[6]+i*768, Gp[7]+i*768,
                      Gp[9]+(size_t)i*3072, Gp[11]+(size_t)i*768,
                      j, N, 8, smap, 149, i==0, ng, nb2);
            N -= 8;
        }
    }
    ln_kernel<<<dim3(N,NB),256,0,stream>>>(xc, g_ng, g_nb, qkvbuf);
    head_k<<<1,128,0,stream>>>(qkvbuf, smap, tmap, head_w, head_b, out);
}